// Round 5
// baseline (263.900 us; speedup 1.0000x reference)
//
#include <hip/hip_runtime.h>
#include <stdint.h>

#define Bz 8
#define Tz 1024
#define Cz 768
#define NHz 12
#define HDz 64

typedef unsigned short u16;
typedef __attribute__((ext_vector_type(8))) __bf16 bf16x8;
typedef __attribute__((ext_vector_type(4))) float f32x4;

__device__ __forceinline__ float bf2f(u16 b) {
    union { uint32_t u; float f; } c; c.u = ((uint32_t)b) << 16; return c.f;
}
__device__ __forceinline__ u16 f2bf(float f) {
    union { float f; uint32_t u; } c; c.f = f;
    uint32_t u = c.u;
    return (u16)((u + 0x7fffu + ((u >> 16) & 1u)) >> 16);
}

// ---------------------------------------------------------------------------
// Fused fp32 -> bf16 elementwise convert for all 4 input tensors (1 launch).
// Region boundaries are multiples of 256 float4s -> wave-uniform branches.
// ---------------------------------------------------------------------------
#define N4_X  (Bz * Tz * Cz / 4)
#define N4_WV (Cz * Cz / 4)
#define N4_WC (Tz * Tz / 4)
#define N4_WP (Cz * Cz / 4)
#define N4_ALL (N4_X + N4_WV + N4_WC + N4_WP)

__global__ __launch_bounds__(256)
void cvt_all(const float* __restrict__ x, const float* __restrict__ wv,
             const float* __restrict__ wc, const float* __restrict__ wp,
             u16* __restrict__ xb, u16* __restrict__ wvb,
             u16* __restrict__ wcb, u16* __restrict__ wpb) {
    int i = blockIdx.x * 256 + threadIdx.x;
    if (i >= N4_ALL) return;
    const float* in;
    u16* out;
    if (i < N4_X) {
        in = x; out = xb;
    } else if (i < N4_X + N4_WV) {
        in = wv; out = wvb; i -= N4_X;
    } else if (i < N4_X + N4_WV + N4_WC) {
        in = wc; out = wcb; i -= N4_X + N4_WV;
    } else {
        in = wp; out = wpb; i -= N4_X + N4_WV + N4_WC;
    }
    float4 v = ((const float4*)in)[i];
    union { u16 h[4]; uint2 u; } o;
    o.h[0] = f2bf(v.x); o.h[1] = f2bf(v.y); o.h[2] = f2bf(v.z); o.h[3] = f2bf(v.w);
    ((uint2*)out)[i] = o.u;
}

// ---------------------------------------------------------------------------
// C = alpha * (A . B^T) [+ bias_col]   MFMA 16x16x32, all-bf16 operands.
// Single-barrier double-buffered K-loop (T3-minimum 2-phase):
//   stage(t+1) issued BEFORE compute(t); one __syncthreads per K-step whose
//   compiler-emitted vmcnt(0) drain lands after the MFMAs, so global->LDS
//   latency hides under compute instead of being exposed at the barrier.
// WAR safety: buf^1's iter-(t-1) ds_reads are lgkmcnt-consumed before that
// iter's barrier; the stage into buf^1 at iter t is issued after it.
// ---------------------------------------------------------------------------
template<int BM, int BN, int WM, int WN, bool OUTF32, bool HASBIAS>
__global__ __launch_bounds__(WM * WN * 64)
void gemm_bt(const u16* __restrict__ A, long long sAz, int lda,
             const u16* __restrict__ Bp, long long sBz, int ldb,
             void* __restrict__ Cp, long long sCz, int ldc,
             const float* __restrict__ bias, int K, float alpha) {
    constexpr int NT = WM * WN * 64;
    constexpr int BK = 32;
    constexpr int AI = (BM * BK) / (NT * 8);
    constexpr int BI = (BN * BK) / (NT * 8);
    static_assert(AI >= 1 && (BM * BK) % (NT * 8) == 0, "A staging");
    static_assert(BI >= 1 && (BN * BK) % (NT * 8) == 0, "B staging");
    static_assert(BM == WM * 64 && BN == WN * 64, "wave tiling");

    __shared__ alignas(16) u16 As[2][BM * BK];
    __shared__ alignas(16) u16 Bs[2][BN * BK];

    const int z = blockIdx.z;
    const u16* Ag = A + (long long)z * sAz;
    const u16* Bg = Bp + (long long)z * sBz;

    const int tid = threadIdx.x;
    const int lane = tid & 63;
    const int w = tid >> 6;
    const int wm = w / WN;
    const int wn = w % WN;
    const int rowBase = blockIdx.y * BM;
    const int colBase = blockIdx.x * BN;
    const int koff = (lane >> 4) * 8;
    const int frow = lane & 15;

    auto stage = [&](int buf, int k0) {
#pragma unroll
        for (int i = 0; i < AI; i++) {
            int e = (i * NT + tid) * 8;
            const u16* g = Ag + (long long)(rowBase + (e >> 5)) * lda + k0 + (e & 31);
            __builtin_amdgcn_global_load_lds(
                (const __attribute__((address_space(1))) uint32_t*)g,
                (__attribute__((address_space(3))) uint32_t*)(&As[buf][0] + e), 16, 0, 0);
        }
#pragma unroll
        for (int i = 0; i < BI; i++) {
            int e = (i * NT + tid) * 8;
            const u16* g = Bg + (long long)(colBase + (e >> 5)) * ldb + k0 + (e & 31);
            __builtin_amdgcn_global_load_lds(
                (const __attribute__((address_space(1))) uint32_t*)g,
                (__attribute__((address_space(3))) uint32_t*)(&Bs[buf][0] + e), 16, 0, 0);
        }
    };

    f32x4 acc[4][4] = {};

    const int nk = K / BK;
    stage(0, 0);
    __syncthreads();   // drain prologue stage (compiler emits vmcnt(0) here)

#pragma unroll 1
    for (int t = 0; t < nk; ++t) {
        const int cur = t & 1;
        if (t + 1 < nk) stage(cur ^ 1, (t + 1) * BK);   // prefetch next tile

        bf16x8 af[4], bfr[4];
#pragma unroll
        for (int mt = 0; mt < 4; mt++)
            af[mt] = *(const bf16x8*)&As[cur][(wm * 64 + mt * 16 + frow) * BK + koff];
#pragma unroll
        for (int nt = 0; nt < 4; nt++)
            bfr[nt] = *(const bf16x8*)&Bs[cur][(wn * 64 + nt * 16 + frow) * BK + koff];
#pragma unroll
        for (int mt = 0; mt < 4; mt++)
#pragma unroll
            for (int nt = 0; nt < 4; nt++)
                acc[mt][nt] = __builtin_amdgcn_mfma_f32_16x16x32_bf16(
                    af[mt], bfr[nt], acc[mt][nt], 0, 0, 0);

        __syncthreads();   // prev reads done + prefetch drained (vmcnt(0))
    }

    const int r0 = rowBase + wm * 64;
    const int c0 = colBase + wn * 64;
    const int rl = (lane >> 4) * 4;
    const int cl = lane & 15;
#pragma unroll
    for (int mt = 0; mt < 4; mt++) {
#pragma unroll
        for (int nt = 0; nt < 4; nt++) {
#pragma unroll
            for (int r = 0; r < 4; r++) {
                int row = r0 + mt * 16 + rl + r;
                int col = c0 + nt * 16 + cl;
                float v = acc[mt][nt][r] * alpha;
                if (HASBIAS) v += bias[col];
                if (OUTF32)
                    ((float*)Cp)[(long long)z * sCz + (long long)row * ldc + col] = v;
                else
                    ((u16*)Cp)[(long long)z * sCz + (long long)row * ldc + col] = f2bf(v);
            }
        }
    }
}

// ---------------------------------------------------------------------------
// Transpose to bf16: in [rows,cols] (fp32 if INF32 else bf16) -> [cols,rows].
// ---------------------------------------------------------------------------
template<bool INF32>
__global__ __launch_bounds__(256)
void transpose_to_bf16(const void* __restrict__ in, u16* __restrict__ out,
                       int rows, int cols, long long sInZ, long long sOutZ) {
    __shared__ u16 tile[32][33];
    const int z = blockIdx.z;
    const int c0 = blockIdx.x * 32, r0 = blockIdx.y * 32;
    const int tx = threadIdx.x, ty = threadIdx.y;
#pragma unroll
    for (int i = 0; i < 32; i += 8) {
        long long off = (long long)z * sInZ + (long long)(r0 + ty + i) * cols + c0 + tx;
        tile[ty + i][tx] = INF32 ? f2bf(((const float*)in)[off]) : ((const u16*)in)[off];
    }
    __syncthreads();
#pragma unroll
    for (int i = 0; i < 32; i += 8)
        out[(long long)z * sOutZ + (long long)(c0 + ty + i) * rows + r0 + tx] = tile[tx][ty + i];
}

// ---------------------------------------------------------------------------
// Fused flash attention v4.
//  - v3 counters: MfmaUtil 9.4, VALUBusy 43.5, Occupancy 18.5% -> latency-
//    bound at 3 blocks/CU (LDS 54.3KB). Fixes:
//  - Vs LDS stage DROPPED: PV reads V fragments directly from global vT.
//    The 16KB V-tile is read by all 4 waves in a tight window (L1/L2-hot),
//    and each dwordx4 is 16 fully-consumed 64B lines (quad-lanes contiguous).
//    LDS 54272 -> 37888 B => 4 blocks/CU residency.
//  - exp2-domain softmax: bcs pre-scaled by log2e, 0.125*log2e folded into
//    the S FMA, exp via v_exp_f32 (exp2) directly. Saves ~36 v_mul/iter.
//  - Us still XOR-chunk-swizzled via global-source side of global_load_lds.
//  - setprio(1) around MFMA clusters (T5, m191).
// In-place y into v is race-free: block reads exactly the region it writes.
// ---------------------------------------------------------------------------
#define LOG2E 1.44269504f

__global__ __launch_bounds__(256)
void flash_attn(const u16* __restrict__ v, const u16* __restrict__ U,
                const u16* __restrict__ vT, const float* __restrict__ bc,
                u16* __restrict__ y) {
    __shared__ alignas(16) u16 Us[128 * 64];    // [key][chunk^key&7] (swizzled)
    __shared__ alignas(16) u16 Ps[64 * 136];    // q x keys, stride 136
    __shared__ float bcs[Tz];                   // bc * log2e

    // grid remap: xcd-affine columns, heavy qi first
    const int bi = blockIdx.x;
    const int xcd = bi & 7;
    const int slot = bi >> 3;                   // 0..191
    const int col = (slot % 12) * 8 + xcd;      // 0..95, col%8 == xcd
    const int qi = 15 - slot / 12;              // heavy tiles first
    const int b = col / NHz, h = col % NHz;

    const int tid = threadIdx.x, lane = tid & 63, w = tid >> 6;
    const int quad = lane >> 4, cl = lane & 15;
    const int q0 = qi * 64;
    const int wrow = w * 16;                    // wave's 16 q-rows

    for (int j = tid; j < Tz; j += 256) bcs[j] = bc[j] * LOG2E;

    // resident A-fragments of vq (this block's own 64x64 slice)
    const u16* vq = v + ((long long)b * Tz + q0) * Cz + h * HDz;
    bf16x8 aS[2];
#pragma unroll
    for (int ks = 0; ks < 2; ks++)
        aS[ks] = *(const bf16x8*)(vq + (long long)(wrow + cl) * Cz + ks * 32 + quad * 8);

    f32x4 Oacc[4] = {};
    float mrow[4], lrow[4];
#pragma unroll
    for (int r = 0; r < 4; r++) { mrow[r] = -3.0e38f; lrow[r] = 0.f; }

    const u16* Ub = U + (long long)b * Tz * Cz + h * HDz;
    const u16* Vb = vT + ((long long)b * Cz + h * HDz) * Tz;

    const int kts = (qi + 2) >> 1;   // # of 128-wide k-tiles covering [0, q0+64)
    for (int kt = 0; kt < kts; kt++) {
        if (kt) __syncthreads();   // prev iter's Us reads complete
        const u16* Ug = Ub + (long long)kt * 128 * Cz;
#pragma unroll
        for (int i = 0; i < 4; i++) {
            int e = (i * 256 + tid) * 8;
            int key = e >> 6;
            int ch = ((e & 63) >> 3) ^ (key & 7);   // global-side swizzle
            __builtin_amdgcn_global_load_lds(
                (const __attribute__((address_space(1))) uint32_t*)(Ug + (long long)key * Cz + ch * 8),
                (__attribute__((address_space(3))) uint32_t*)(Us + e), 16, 0, 0);
        }
        __syncthreads();

        // S = vq . Uk^T  (wave tile 16 x 128)
        f32x4 S[8] = {};
        __builtin_amdgcn_s_setprio(1);
#pragma unroll
        for (int ks = 0; ks < 2; ks++)
#pragma unroll
            for (int nt = 0; nt < 8; nt++) {
                int key = nt * 16 + cl;
                bf16x8 bS = *(const bf16x8*)&Us[key * 64 + (((ks * 4 + quad) ^ (key & 7)) * 8)];
                S[nt] = __builtin_amdgcn_mfma_f32_16x16x32_bf16(aS[ks], bS, S[nt], 0, 0, 0);
            }
        __builtin_amdgcn_s_setprio(0);

        const bool last = (kt == kts - 1);
#pragma unroll
        for (int nt = 0; nt < 8; nt++)
#pragma unroll
            for (int r = 0; r < 4; r++) {
                int rowg = q0 + wrow + quad * 4 + r;
                int colg = kt * 128 + nt * 16 + cl;
                // log2 domain: s2 = S*(0.125*log2e) + bc*log2e
                float s = S[nt][r] * (0.125f * LOG2E) + bcs[colg];
                if (last && colg > rowg) s = -3.0e38f;
                S[nt][r] = s;
            }

        // row max (regs, then across the 16 lanes of the quad group)
        float mnew[4], alpha[4];
#pragma unroll
        for (int r = 0; r < 4; r++) {
            float m = S[0][r];
#pragma unroll
            for (int nt = 1; nt < 8; nt++) m = fmaxf(m, S[nt][r]);
#pragma unroll
            for (int d = 1; d < 16; d <<= 1) m = fmaxf(m, __shfl_xor(m, d));
            mnew[r] = fmaxf(mrow[r], m);
            alpha[r] = __builtin_amdgcn_exp2f(mrow[r] - mnew[r]);
            mrow[r] = mnew[r];
        }

        // P = exp2(S - m) -> LDS (wave-private rows), accumulate row sums
        float psum[4] = {};
#pragma unroll
        for (int nt = 0; nt < 8; nt++)
#pragma unroll
            for (int r = 0; r < 4; r++) {
                float p = __builtin_amdgcn_exp2f(S[nt][r] - mnew[r]);
                psum[r] += p;
                Ps[(wrow + quad * 4 + r) * 136 + nt * 16 + cl] = f2bf(p);
            }
#pragma unroll
        for (int r = 0; r < 4; r++) {
            float s = psum[r];
#pragma unroll
            for (int d = 1; d < 16; d <<= 1) s += __shfl_xor(s, d);
            lrow[r] = lrow[r] * alpha[r] + s;
#pragma unroll
            for (int nt2 = 0; nt2 < 4; nt2++)
                Oacc[nt2][r] *= alpha[r];
        }

        // no barrier: Ps rows are wave-private; same-wave DS ordering suffices

        // O += P . Vk   (K = 128), V fragments straight from global (L1/L2-hot)
        __builtin_amdgcn_s_setprio(1);
#pragma unroll
        for (int ks = 0; ks < 4; ks++) {
            bf16x8 pA = *(const bf16x8*)&Ps[(wrow + cl) * 136 + ks * 32 + quad * 8];
#pragma unroll
            for (int nt2 = 0; nt2 < 4; nt2++) {
                const u16* Vrow = Vb + (long long)(nt2 * 16 + cl) * Tz + kt * 128 + (ks * 4 + quad) * 8;
                bf16x8 vB = *(const bf16x8*)Vrow;
                Oacc[nt2] = __builtin_amdgcn_mfma_f32_16x16x32_bf16(pA, vB, Oacc[nt2], 0, 0, 0);
            }
        }
        __builtin_amdgcn_s_setprio(0);
    }

    // epilogue: O /= l, write y (in-place into v's own region)
    u16* yq = y + ((long long)b * Tz + q0) * Cz + h * HDz;
#pragma unroll
    for (int r = 0; r < 4; r++) {
        float inv = 1.f / lrow[r];
#pragma unroll
        for (int nt2 = 0; nt2 < 4; nt2++)
            yq[(long long)(wrow + quad * 4 + r) * Cz + nt2 * 16 + cl] =
                f2bf(Oacc[nt2][r] * inv);
    }
}

// ---------------------------------------------------------------------------
extern "C" void kernel_launch(void* const* d_in, const int* in_sizes, int n_in,
                              void* d_out, int out_size, void* d_ws, size_t ws_size,
                              hipStream_t stream) {
    const float* x  = (const float*)d_in[0];
    const float* Wv = (const float*)d_in[1];
    const float* bv = (const float*)d_in[2];
    const float* Wl = (const float*)d_in[3];
    const float* Wc = (const float*)d_in[4];
    const float* bc = (const float*)d_in[5];
    const float* Wp = (const float*)d_in[6];
    const float* bp = (const float*)d_in[7];

    // ws (bf16 elems, ~59 MB): xb, Wvb, Wcb, Wpb, WlT, Wcl, vbf, vT, U
    u16* ws  = (u16*)d_ws;
    u16* xb  = ws;
    u16* Wvb = xb  + (size_t)Bz * Tz * Cz;
    u16* Wcb = Wvb + (size_t)Cz * Cz;
    u16* Wpb = Wcb + (size_t)Tz * Tz;
    u16* WlT = Wpb + (size_t)Cz * Cz;
    u16* Wcl = WlT + (size_t)Tz * Tz;
    u16* vbf = Wcl + (size_t)Tz * Tz;
    u16* vT  = vbf + (size_t)Bz * Tz * Cz;
    u16* U   = vT  + (size_t)Bz * Tz * Cz;

    const long long sTC = (long long)Tz * Cz;
    const long long sCT = (long long)Cz * Tz;

    // 0) one-time bf16 conversions (single fused launch)
    cvt_all<<<(N4_ALL + 255) / 256, 256, 0, stream>>>(x, Wv, Wc, Wp, xb, Wvb, Wcb, Wpb);
    // 1) WlT = Wl^T (fp32 -> bf16)
    transpose_to_bf16<true><<<dim3(32, 32, 1), dim3(32, 8), 0, stream>>>(Wl, WlT, Tz, Tz, 0, 0);
    // 2) Wcl = Wcb . WlT^T = Wc @ Wl — 64^2 tile: 256 blocks = 1/CU
    gemm_bt<64, 64, 1, 1, false, false><<<dim3(Tz / 64, Tz / 64, 1), 64, 0, stream>>>(
        Wcb, 0, Tz, WlT, 0, Tz, Wcl, 0, Tz, nullptr, Tz, 1.f);
    // 3) v = xb . Wvb^T + bv
    gemm_bt<128, 128, 2, 2, false, true><<<dim3(Cz / 128, (Bz * Tz) / 128, 1), 256, 0, stream>>>(
        xb, 0, Cz, Wvb, 0, Cz, vbf, 0, Cz, bv, Cz, 1.f);
    // 4) vT[b] = v[b]^T
    transpose_to_bf16<false><<<dim3(Cz / 32, Tz / 32, Bz), dim3(32, 8), 0, stream>>>(
        vbf, vT, Tz, Cz, sTC, sCT);
    // 5) U[b] = Wcl @ v[b]  (= Wcl . vT[b]^T), K=T
    gemm_bt<128, 128, 2, 2, false, false><<<dim3(Cz / 128, Tz / 128, Bz), 256, 0, stream>>>(
        Wcl, 0, Tz, vT, sCT, Tz, U, sTC, Cz, nullptr, Tz, 1.f);
    // 6) fused logits -> causal softmax -> P.V, y in-place into vbf
    flash_attn<<<dim3((Tz / 64) * NHz * Bz, 1, 1), 256, 0, stream>>>(vbf, U, vT, bc, vbf);
    // 7) out = y . Wpb^T + bp  (fp32 out)
    gemm_bt<128, 128, 2, 2, true, true><<<dim3(Cz / 128, (Bz * Tz) / 128, 1), 256, 0, stream>>>(
        vbf, 0, Cz, Wpb, 0, Cz, (float*)d_out, 0, Cz, bp, Cz, 1.f);
}

// Round 7
// 236.364 us; speedup vs baseline: 1.1165x; 1.1165x over previous
//
#include <hip/hip_runtime.h>
#include <stdint.h>

#define Bz 8
#define Tz 1024
#define Cz 768
#define NHz 12
#define HDz 64

typedef unsigned short u16;
typedef __attribute__((ext_vector_type(8))) __bf16 bf16x8;
typedef __attribute__((ext_vector_type(4))) float f32x4;

__device__ __forceinline__ float bf2f(u16 b) {
    union { uint32_t u; float f; } c; c.u = ((uint32_t)b) << 16; return c.f;
}
__device__ __forceinline__ u16 f2bf(float f) {
    union { float f; uint32_t u; } c; c.f = f;
    uint32_t u = c.u;
    return (u16)((u + 0x7fffu + ((u >> 16) & 1u)) >> 16);
}

// ---------------------------------------------------------------------------
// Fused fp32 -> bf16 elementwise convert for all 4 input tensors (1 launch).
// ---------------------------------------------------------------------------
#define N4_X  (Bz * Tz * Cz / 4)
#define N4_WV (Cz * Cz / 4)
#define N4_WC (Tz * Tz / 4)
#define N4_WP (Cz * Cz / 4)
#define N4_ALL (N4_X + N4_WV + N4_WC + N4_WP)

__global__ __launch_bounds__(256)
void cvt_all(const float* __restrict__ x, const float* __restrict__ wv,
             const float* __restrict__ wc, const float* __restrict__ wp,
             u16* __restrict__ xb, u16* __restrict__ wvb,
             u16* __restrict__ wcb, u16* __restrict__ wpb) {
    int i = blockIdx.x * 256 + threadIdx.x;
    if (i >= N4_ALL) return;
    const float* in;
    u16* out;
    if (i < N4_X) {
        in = x; out = xb;
    } else if (i < N4_X + N4_WV) {
        in = wv; out = wvb; i -= N4_X;
    } else if (i < N4_X + N4_WV + N4_WC) {
        in = wc; out = wcb; i -= N4_X + N4_WV;
    } else {
        in = wp; out = wpb; i -= N4_X + N4_WV + N4_WC;
    }
    float4 v = ((const float4*)in)[i];
    union { u16 h[4]; uint2 u; } o;
    o.h[0] = f2bf(v.x); o.h[1] = f2bf(v.y); o.h[2] = f2bf(v.z); o.h[3] = f2bf(v.w);
    ((uint2*)out)[i] = o.u;
}

// ---------------------------------------------------------------------------
// C = alpha * (A . B^T) [+ bias_col]   MFMA 16x16x32, all-bf16 operands.
// Single-barrier double-buffered K-loop (2-phase).
// ---------------------------------------------------------------------------
template<int BM, int BN, int WM, int WN, bool OUTF32, bool HASBIAS>
__global__ __launch_bounds__(WM * WN * 64)
void gemm_bt(const u16* __restrict__ A, long long sAz, int lda,
             const u16* __restrict__ Bp, long long sBz, int ldb,
             void* __restrict__ Cp, long long sCz, int ldc,
             const float* __restrict__ bias, int K, float alpha) {
    constexpr int NT = WM * WN * 64;
    constexpr int BK = 32;
    constexpr int AI = (BM * BK) / (NT * 8);
    constexpr int BI = (BN * BK) / (NT * 8);
    static_assert(AI >= 1 && (BM * BK) % (NT * 8) == 0, "A staging");
    static_assert(BI >= 1 && (BN * BK) % (NT * 8) == 0, "B staging");
    static_assert(BM == WM * 64 && BN == WN * 64, "wave tiling");

    __shared__ alignas(16) u16 As[2][BM * BK];
    __shared__ alignas(16) u16 Bs[2][BN * BK];

    const int z = blockIdx.z;
    const u16* Ag = A + (long long)z * sAz;
    const u16* Bg = Bp + (long long)z * sBz;

    const int tid = threadIdx.x;
    const int lane = tid & 63;
    const int w = tid >> 6;
    const int wm = w / WN;
    const int wn = w % WN;
    const int rowBase = blockIdx.y * BM;
    const int colBase = blockIdx.x * BN;
    const int koff = (lane >> 4) * 8;
    const int frow = lane & 15;

    auto stage = [&](int buf, int k0) {
#pragma unroll
        for (int i = 0; i < AI; i++) {
            int e = (i * NT + tid) * 8;
            const u16* g = Ag + (long long)(rowBase + (e >> 5)) * lda + k0 + (e & 31);
            __builtin_amdgcn_global_load_lds(
                (const __attribute__((address_space(1))) uint32_t*)g,
                (__attribute__((address_space(3))) uint32_t*)(&As[buf][0] + e), 16, 0, 0);
        }
#pragma unroll
        for (int i = 0; i < BI; i++) {
            int e = (i * NT + tid) * 8;
            const u16* g = Bg + (long long)(colBase + (e >> 5)) * ldb + k0 + (e & 31);
            __builtin_amdgcn_global_load_lds(
                (const __attribute__((address_space(1))) uint32_t*)g,
                (__attribute__((address_space(3))) uint32_t*)(&Bs[buf][0] + e), 16, 0, 0);
        }
    };

    f32x4 acc[4][4] = {};

    const int nk = K / BK;
    stage(0, 0);
    __syncthreads();

#pragma unroll 1
    for (int t = 0; t < nk; ++t) {
        const int cur = t & 1;
        if (t + 1 < nk) stage(cur ^ 1, (t + 1) * BK);

        bf16x8 af[4], bfr[4];
#pragma unroll
        for (int mt = 0; mt < 4; mt++)
            af[mt] = *(const bf16x8*)&As[cur][(wm * 64 + mt * 16 + frow) * BK + koff];
#pragma unroll
        for (int nt = 0; nt < 4; nt++)
            bfr[nt] = *(const bf16x8*)&Bs[cur][(wn * 64 + nt * 16 + frow) * BK + koff];
#pragma unroll
        for (int mt = 0; mt < 4; mt++)
#pragma unroll
            for (int nt = 0; nt < 4; nt++)
                acc[mt][nt] = __builtin_amdgcn_mfma_f32_16x16x32_bf16(
                    af[mt], bfr[nt], acc[mt][nt], 0, 0, 0);

        __syncthreads();
    }

    const int r0 = rowBase + wm * 64;
    const int c0 = colBase + wn * 64;
    const int rl = (lane >> 4) * 4;
    const int cl = lane & 15;
#pragma unroll
    for (int mt = 0; mt < 4; mt++) {
#pragma unroll
        for (int nt = 0; nt < 4; nt++) {
#pragma unroll
            for (int r = 0; r < 4; r++) {
                int row = r0 + mt * 16 + rl + r;
                int col = c0 + nt * 16 + cl;
                float v = acc[mt][nt][r] * alpha;
                if (HASBIAS) v += bias[col];
                if (OUTF32)
                    ((float*)Cp)[(long long)z * sCz + (long long)row * ldc + col] = v;
                else
                    ((u16*)Cp)[(long long)z * sCz + (long long)row * ldc + col] = f2bf(v);
            }
        }
    }
}

// ---------------------------------------------------------------------------
// Transpose to bf16: in [rows,cols] (fp32 if INF32 else bf16) -> [cols,rows].
// ---------------------------------------------------------------------------
template<bool INF32>
__global__ __launch_bounds__(256)
void transpose_to_bf16(const void* __restrict__ in, u16* __restrict__ out,
                       int rows, int cols, long long sInZ, long long sOutZ) {
    __shared__ u16 tile[32][33];
    const int z = blockIdx.z;
    const int c0 = blockIdx.x * 32, r0 = blockIdx.y * 32;
    const int tx = threadIdx.x, ty = threadIdx.y;
#pragma unroll
    for (int i = 0; i < 32; i += 8) {
        long long off = (long long)z * sInZ + (long long)(r0 + ty + i) * cols + c0 + tx;
        tile[ty + i][tx] = INF32 ? f2bf(((const float*)in)[off]) : ((const u16*)in)[off];
    }
    __syncthreads();
#pragma unroll
    for (int i = 0; i < 32; i += 8)
        out[(long long)z * sOutZ + (long long)(c0 + ty + i) * rows + r0 + tx] = tile[tx][ty + i];
}

// ---------------------------------------------------------------------------
// Fused flash attention v5.
//  - v4 POST-MORTEM: V-direct-from-global PV regressed 57->78us (VMEM latency
//    in the MFMA consume path). REVERTED: Vs staged in LDS again (swizzled
//    global_load_lds). Keep exp2 softmax (pure VALU win).
//  - NEW split-wait pipeline (T4, vmcnt in-order semantics per m135):
//      stage Us(4) then Vs(4); vmcnt(4)+s_barrier -> S-MFMA runs with Vs
//      STILL IN FLIGHT; after softmax vmcnt(0)+s_barrier -> PV.
//    Vs staging latency hides under ~800cy of S-MFMA+softmax instead of
//    draining at one barrier (the m97-style stall).
//  - bcs stored as bf16 (bc==0 in this problem; exact): LDS 54272->52224 B
//    => 3 blocks/CU residency (was 2).
//  - setprio(1) around MFMA clusters (T5).
// In-place y into v is race-free: block reads exactly the region it writes.
// ---------------------------------------------------------------------------
#define LOG2E 1.44269504f

__global__ __launch_bounds__(256)
void flash_attn(const u16* __restrict__ v, const u16* __restrict__ U,
                const u16* __restrict__ vT, const float* __restrict__ bc,
                u16* __restrict__ y) {
    __shared__ alignas(16) u16 Us[128 * 64];    // [key][chunk^key&7] (swizzled)
    __shared__ alignas(16) u16 Vs[64 * 128];    // [dim][chunk^dim&15] (swizzled)
    __shared__ alignas(16) u16 Ps[64 * 136];    // q x keys, stride 136
    __shared__ u16 bcs[Tz];                     // bf16(bc * log2e)

    // grid remap: xcd-affine columns, heavy qi first
    const int bi = blockIdx.x;
    const int xcd = bi & 7;
    const int slot = bi >> 3;                   // 0..191
    const int col = (slot % 12) * 8 + xcd;      // 0..95, col%8 == xcd
    const int qi = 15 - slot / 12;              // heavy tiles first
    const int b = col / NHz, h = col % NHz;

    const int tid = threadIdx.x, lane = tid & 63, w = tid >> 6;
    const int quad = lane >> 4, cl = lane & 15;
    const int q0 = qi * 64;
    const int wrow = w * 16;                    // wave's 16 q-rows

    for (int j = tid; j < Tz; j += 256) bcs[j] = f2bf(bc[j] * LOG2E);

    // resident A-fragments of vq (this block's own 64x64 slice)
    const u16* vq = v + ((long long)b * Tz + q0) * Cz + h * HDz;
    bf16x8 aS[2];
#pragma unroll
    for (int ks = 0; ks < 2; ks++)
        aS[ks] = *(const bf16x8*)(vq + (long long)(wrow + cl) * Cz + ks * 32 + quad * 8);

    f32x4 Oacc[4] = {};
    float mrow[4], lrow[4];
#pragma unroll
    for (int r = 0; r < 4; r++) { mrow[r] = -3.0e38f; lrow[r] = 0.f; }

    const u16* Ub = U + (long long)b * Tz * Cz + h * HDz;
    const u16* Vb = vT + ((long long)b * Cz + h * HDz) * Tz;

    __syncthreads();   // bcs visible to all waves; drains pre-loop VMEM

    const int kts = (qi + 2) >> 1;   // # of 128-wide k-tiles covering [0, q0+64)
    for (int kt = 0; kt < kts; kt++) {
        if (kt) __builtin_amdgcn_s_barrier();   // WAR: all waves done reading Us/Vs
        const u16* Ug = Ub + (long long)kt * 128 * Cz;
#pragma unroll
        for (int i = 0; i < 4; i++) {           // Us first (waited by vmcnt(4))
            int e = (i * 256 + tid) * 8;
            int key = e >> 6;
            int ch = ((e & 63) >> 3) ^ (key & 7);   // global-side swizzle
            __builtin_amdgcn_global_load_lds(
                (const __attribute__((address_space(1))) uint32_t*)(Ug + (long long)key * Cz + ch * 8),
                (__attribute__((address_space(3))) uint32_t*)(Us + e), 16, 0, 0);
        }
        const u16* Vg = Vb + kt * 128;
#pragma unroll
        for (int i = 0; i < 4; i++) {           // Vs second (stays in flight)
            int e = (i * 256 + tid) * 8;
            int dim = e >> 7;
            int ch = ((e & 127) >> 3) ^ (dim & 15);  // global-side swizzle
            __builtin_amdgcn_global_load_lds(
                (const __attribute__((address_space(1))) uint32_t*)(Vg + (long long)dim * Tz + ch * 8),
                (__attribute__((address_space(3))) uint32_t*)(Vs + e), 16, 0, 0);
        }
        // own Us landed (in-order retire); Vs (newest 4) may still be in flight
        asm volatile("s_waitcnt vmcnt(4)" ::: "memory");
        __builtin_amdgcn_s_barrier();           // all waves' Us landed

        // S = vq . Uk^T  (wave tile 16 x 128) — overlaps Vs flight time
        f32x4 S[8] = {};
        __builtin_amdgcn_s_setprio(1);
#pragma unroll
        for (int ks = 0; ks < 2; ks++)
#pragma unroll
            for (int nt = 0; nt < 8; nt++) {
                int key = nt * 16 + cl;
                bf16x8 bS = *(const bf16x8*)&Us[key * 64 + (((ks * 4 + quad) ^ (key & 7)) * 8)];
                S[nt] = __builtin_amdgcn_mfma_f32_16x16x32_bf16(aS[ks], bS, S[nt], 0, 0, 0);
            }
        __builtin_amdgcn_s_setprio(0);

        const bool last = (kt == kts - 1);
#pragma unroll
        for (int nt = 0; nt < 8; nt++) {
            float bl = bf2f(bcs[kt * 128 + nt * 16 + cl]);
#pragma unroll
            for (int r = 0; r < 4; r++) {
                int rowg = q0 + wrow + quad * 4 + r;
                int colg = kt * 128 + nt * 16 + cl;
                // log2 domain: s2 = S*(0.125*log2e) + bc*log2e
                float s = S[nt][r] * (0.125f * LOG2E) + bl;
                if (last && colg > rowg) s = -3.0e38f;
                S[nt][r] = s;
            }
        }

        // row max (regs, then across the 16 lanes of the quad group)
        float mnew[4], alpha[4];
#pragma unroll
        for (int r = 0; r < 4; r++) {
            float m = S[0][r];
#pragma unroll
            for (int nt = 1; nt < 8; nt++) m = fmaxf(m, S[nt][r]);
#pragma unroll
            for (int d = 1; d < 16; d <<= 1) m = fmaxf(m, __shfl_xor(m, d));
            mnew[r] = fmaxf(mrow[r], m);
            alpha[r] = __builtin_amdgcn_exp2f(mrow[r] - mnew[r]);
            mrow[r] = mnew[r];
        }

        // P = exp2(S - m) -> LDS (wave-private rows), accumulate row sums
        float psum[4] = {};
#pragma unroll
        for (int nt = 0; nt < 8; nt++)
#pragma unroll
            for (int r = 0; r < 4; r++) {
                float p = __builtin_amdgcn_exp2f(S[nt][r] - mnew[r]);
                psum[r] += p;
                Ps[(wrow + quad * 4 + r) * 136 + nt * 16 + cl] = f2bf(p);
            }
#pragma unroll
        for (int r = 0; r < 4; r++) {
            float s = psum[r];
#pragma unroll
            for (int d = 1; d < 16; d <<= 1) s += __shfl_xor(s, d);
            lrow[r] = lrow[r] * alpha[r] + s;
#pragma unroll
            for (int nt2 = 0; nt2 < 4; nt2++)
                Oacc[nt2][r] *= alpha[r];
        }

        // own Vs landed; barrier -> all waves' Vs landed
        asm volatile("s_waitcnt vmcnt(0)" ::: "memory");
        __builtin_amdgcn_s_barrier();

        // O += P . Vk   (K = 128)
        __builtin_amdgcn_s_setprio(1);
#pragma unroll
        for (int ks = 0; ks < 4; ks++) {
            bf16x8 pA = *(const bf16x8*)&Ps[(wrow + cl) * 136 + ks * 32 + quad * 8];
#pragma unroll
            for (int nt2 = 0; nt2 < 4; nt2++) {
                int dim = nt2 * 16 + cl;
                bf16x8 vB = *(const bf16x8*)&Vs[dim * 128 + (((ks * 4 + quad) ^ cl) * 8)];
                Oacc[nt2] = __builtin_amdgcn_mfma_f32_16x16x32_bf16(pA, vB, Oacc[nt2], 0, 0, 0);
            }
        }
        __builtin_amdgcn_s_setprio(0);
    }

    // epilogue: O /= l, write y (in-place into v's own region)
    u16* yq = y + ((long long)b * Tz + q0) * Cz + h * HDz;
#pragma unroll
    for (int r = 0; r < 4; r++) {
        float inv = 1.f / lrow[r];
#pragma unroll
        for (int nt2 = 0; nt2 < 4; nt2++)
            yq[(long long)(wrow + quad * 4 + r) * Cz + nt2 * 16 + cl] =
                f2bf(Oacc[nt2][r] * inv);
    }
}

// ---------------------------------------------------------------------------
extern "C" void kernel_launch(void* const* d_in, const int* in_sizes, int n_in,
                              void* d_out, int out_size, void* d_ws, size_t ws_size,
                              hipStream_t stream) {
    const float* x  = (const float*)d_in[0];
    const float* Wv = (const float*)d_in[1];
    const float* bv = (const float*)d_in[2];
    const float* Wl = (const float*)d_in[3];
    const float* Wc = (const float*)d_in[4];
    const float* bc = (const float*)d_in[5];
    const float* Wp = (const float*)d_in[6];
    const float* bp = (const float*)d_in[7];

    // ws (bf16 elems, ~59 MB): xb, Wvb, Wcb, Wpb, WlT, Wcl, vbf, vT, U
    u16* ws  = (u16*)d_ws;
    u16* xb  = ws;
    u16* Wvb = xb  + (size_t)Bz * Tz * Cz;
    u16* Wcb = Wvb + (size_t)Cz * Cz;
    u16* Wpb = Wcb + (size_t)Tz * Tz;
    u16* WlT = Wpb + (size_t)Cz * Cz;
    u16* Wcl = WlT + (size_t)Tz * Tz;
    u16* vbf = Wcl + (size_t)Tz * Tz;
    u16* vT  = vbf + (size_t)Bz * Tz * Cz;
    u16* U   = vT  + (size_t)Bz * Tz * Cz;

    const long long sTC = (long long)Tz * Cz;
    const long long sCT = (long long)Cz * Tz;

    // 0) one-time bf16 conversions (single fused launch)
    cvt_all<<<(N4_ALL + 255) / 256, 256, 0, stream>>>(x, Wv, Wc, Wp, xb, Wvb, Wcb, Wpb);
    // 1) WlT = Wl^T (fp32 -> bf16)
    transpose_to_bf16<true><<<dim3(32, 32, 1), dim3(32, 8), 0, stream>>>(Wl, WlT, Tz, Tz, 0, 0);
    // 2) Wcl = Wcb . WlT^T = Wc @ Wl — 64^2 tile: 256 blocks = 1/CU
    gemm_bt<64, 64, 1, 1, false, false><<<dim3(Tz / 64, Tz / 64, 1), 64, 0, stream>>>(
        Wcb, 0, Tz, WlT, 0, Tz, Wcl, 0, Tz, nullptr, Tz, 1.f);
    // 3) v = xb . Wvb^T + bv
    gemm_bt<128, 128, 2, 2, false, true><<<dim3(Cz / 128, (Bz * Tz) / 128, 1), 256, 0, stream>>>(
        xb, 0, Cz, Wvb, 0, Cz, vbf, 0, Cz, bv, Cz, 1.f);
    // 4) vT[b] = v[b]^T
    transpose_to_bf16<false><<<dim3(Cz / 32, Tz / 32, Bz), dim3(32, 8), 0, stream>>>(
        vbf, vT, Tz, Cz, sTC, sCT);
    // 5) U[b] = Wcl @ v[b]  (= Wcl . vT[b]^T), K=T
    gemm_bt<128, 128, 2, 2, false, false><<<dim3(Cz / 128, Tz / 128, Bz), 256, 0, stream>>>(
        Wcl, 0, Tz, vT, sCT, Tz, U, sTC, Cz, nullptr, Tz, 1.f);
    // 6) fused logits -> causal softmax -> P.V, y in-place into vbf
    flash_attn<<<dim3((Tz / 64) * NHz * Bz, 1, 1), 256, 0, stream>>>(vbf, U, vT, bc, vbf);
    // 7) out = y . Wpb^T + bp  (fp32 out)
    gemm_bt<128, 128, 2, 2, true, true><<<dim3(Cz / 128, (Bz * Tz) / 128, 1), 256, 0, stream>>>(
        vbf, 0, Cz, Wpb, 0, Cz, (float*)d_out, 0, Cz, bp, Cz, 1.f);
}

// Round 9
// 235.619 us; speedup vs baseline: 1.1200x; 1.0032x over previous
//
#include <hip/hip_runtime.h>
#include <stdint.h>

#define Bz 8
#define Tz 1024
#define Cz 768
#define NHz 12
#define HDz 64

typedef unsigned short u16;
typedef __attribute__((ext_vector_type(8))) __bf16 bf16x8;
typedef __attribute__((ext_vector_type(4))) float f32x4;

__device__ __forceinline__ float bf2f(u16 b) {
    union { uint32_t u; float f; } c; c.u = ((uint32_t)b) << 16; return c.f;
}
__device__ __forceinline__ u16 f2bf(float f) {
    union { float f; uint32_t u; } c; c.f = f;
    uint32_t u = c.u;
    return (u16)((u + 0x7fffu + ((u >> 16) & 1u)) >> 16);
}

// ---------------------------------------------------------------------------
// Fused fp32 -> bf16 elementwise convert for all 4 input tensors (1 launch).
// ---------------------------------------------------------------------------
#define N4_X  (Bz * Tz * Cz / 4)
#define N4_WV (Cz * Cz / 4)
#define N4_WC (Tz * Tz / 4)
#define N4_WP (Cz * Cz / 4)
#define N4_ALL (N4_X + N4_WV + N4_WC + N4_WP)

__global__ __launch_bounds__(256)
void cvt_all(const float* __restrict__ x, const float* __restrict__ wv,
             const float* __restrict__ wc, const float* __restrict__ wp,
             u16* __restrict__ xb, u16* __restrict__ wvb,
             u16* __restrict__ wcb, u16* __restrict__ wpb) {
    int i = blockIdx.x * 256 + threadIdx.x;
    if (i >= N4_ALL) return;
    const float* in;
    u16* out;
    if (i < N4_X) {
        in = x; out = xb;
    } else if (i < N4_X + N4_WV) {
        in = wv; out = wvb; i -= N4_X;
    } else if (i < N4_X + N4_WV + N4_WC) {
        in = wc; out = wcb; i -= N4_X + N4_WV;
    } else {
        in = wp; out = wpb; i -= N4_X + N4_WV + N4_WC;
    }
    float4 v = ((const float4*)in)[i];
    union { u16 h[4]; uint2 u; } o;
    o.h[0] = f2bf(v.x); o.h[1] = f2bf(v.y); o.h[2] = f2bf(v.z); o.h[3] = f2bf(v.w);
    ((uint2*)out)[i] = o.u;
}

// ---------------------------------------------------------------------------
// C = alpha * (A . B^T) [+ bias_col]   MFMA 16x16x32, all-bf16 operands.
// Single-barrier double-buffered K-loop (2-phase).
// ---------------------------------------------------------------------------
template<int BM, int BN, int WM, int WN, bool OUTF32, bool HASBIAS>
__global__ __launch_bounds__(WM * WN * 64)
void gemm_bt(const u16* __restrict__ A, long long sAz, int lda,
             const u16* __restrict__ Bp, long long sBz, int ldb,
             void* __restrict__ Cp, long long sCz, int ldc,
             const float* __restrict__ bias, int K, float alpha) {
    constexpr int NT = WM * WN * 64;
    constexpr int BK = 32;
    constexpr int AI = (BM * BK) / (NT * 8);
    constexpr int BI = (BN * BK) / (NT * 8);
    static_assert(AI >= 1 && (BM * BK) % (NT * 8) == 0, "A staging");
    static_assert(BI >= 1 && (BN * BK) % (NT * 8) == 0, "B staging");
    static_assert(BM == WM * 64 && BN == WN * 64, "wave tiling");

    __shared__ alignas(16) u16 As[2][BM * BK];
    __shared__ alignas(16) u16 Bs[2][BN * BK];

    const int z = blockIdx.z;
    const u16* Ag = A + (long long)z * sAz;
    const u16* Bg = Bp + (long long)z * sBz;

    const int tid = threadIdx.x;
    const int lane = tid & 63;
    const int w = tid >> 6;
    const int wm = w / WN;
    const int wn = w % WN;
    const int rowBase = blockIdx.y * BM;
    const int colBase = blockIdx.x * BN;
    const int koff = (lane >> 4) * 8;
    const int frow = lane & 15;

    auto stage = [&](int buf, int k0) {
#pragma unroll
        for (int i = 0; i < AI; i++) {
            int e = (i * NT + tid) * 8;
            const u16* g = Ag + (long long)(rowBase + (e >> 5)) * lda + k0 + (e & 31);
            __builtin_amdgcn_global_load_lds(
                (const __attribute__((address_space(1))) uint32_t*)g,
                (__attribute__((address_space(3))) uint32_t*)(&As[buf][0] + e), 16, 0, 0);
        }
#pragma unroll
        for (int i = 0; i < BI; i++) {
            int e = (i * NT + tid) * 8;
            const u16* g = Bg + (long long)(colBase + (e >> 5)) * ldb + k0 + (e & 31);
            __builtin_amdgcn_global_load_lds(
                (const __attribute__((address_space(1))) uint32_t*)g,
                (__attribute__((address_space(3))) uint32_t*)(&Bs[buf][0] + e), 16, 0, 0);
        }
    };

    f32x4 acc[4][4] = {};

    const int nk = K / BK;
    stage(0, 0);
    __syncthreads();

#pragma unroll 1
    for (int t = 0; t < nk; ++t) {
        const int cur = t & 1;
        if (t + 1 < nk) stage(cur ^ 1, (t + 1) * BK);

        bf16x8 af[4], bfr[4];
#pragma unroll
        for (int mt = 0; mt < 4; mt++)
            af[mt] = *(const bf16x8*)&As[cur][(wm * 64 + mt * 16 + frow) * BK + koff];
#pragma unroll
        for (int nt = 0; nt < 4; nt++)
            bfr[nt] = *(const bf16x8*)&Bs[cur][(wn * 64 + nt * 16 + frow) * BK + koff];
#pragma unroll
        for (int mt = 0; mt < 4; mt++)
#pragma unroll
            for (int nt = 0; nt < 4; nt++)
                acc[mt][nt] = __builtin_amdgcn_mfma_f32_16x16x32_bf16(
                    af[mt], bfr[nt], acc[mt][nt], 0, 0, 0);

        __syncthreads();
    }

    const int r0 = rowBase + wm * 64;
    const int c0 = colBase + wn * 64;
    const int rl = (lane >> 4) * 4;
    const int cl = lane & 15;
#pragma unroll
    for (int mt = 0; mt < 4; mt++) {
#pragma unroll
        for (int nt = 0; nt < 4; nt++) {
#pragma unroll
            for (int r = 0; r < 4; r++) {
                int row = r0 + mt * 16 + rl + r;
                int col = c0 + nt * 16 + cl;
                float v = acc[mt][nt][r] * alpha;
                if (HASBIAS) v += bias[col];
                if (OUTF32)
                    ((float*)Cp)[(long long)z * sCz + (long long)row * ldc + col] = v;
                else
                    ((u16*)Cp)[(long long)z * sCz + (long long)row * ldc + col] = f2bf(v);
            }
        }
    }
}

// ---------------------------------------------------------------------------
// Transpose to bf16: in [rows,cols] (fp32 if INF32 else bf16) -> [cols,rows].
// ---------------------------------------------------------------------------
template<bool INF32>
__global__ __launch_bounds__(256)
void transpose_to_bf16(const void* __restrict__ in, u16* __restrict__ out,
                       int rows, int cols, long long sInZ, long long sOutZ) {
    __shared__ u16 tile[32][33];
    const int z = blockIdx.z;
    const int c0 = blockIdx.x * 32, r0 = blockIdx.y * 32;
    const int tx = threadIdx.x, ty = threadIdx.y;
#pragma unroll
    for (int i = 0; i < 32; i += 8) {
        long long off = (long long)z * sInZ + (long long)(r0 + ty + i) * cols + c0 + tx;
        tile[ty + i][tx] = INF32 ? f2bf(((const float*)in)[off]) : ((const u16*)in)[off];
    }
    __syncthreads();
#pragma unroll
    for (int i = 0; i < 32; i += 8)
        out[(long long)z * sOutZ + (long long)(c0 + ty + i) * rows + r0 + tx] = tile[tx][ty + i];
}

// ---------------------------------------------------------------------------
// Fused flash attention v6: QBLK 64 -> 128 (8 waves).
//  - v5 measured: 53.4us, MfmaUtil 10.2, Occ 25.1 -> still staging/latency
//    dominated. Each K/V tile now staged once per 128 q-rows: tile-iters
//    halve (72 -> 36 per column), staging bytes and barriers halve.
//  - LDS 69632 B -> 2 blocks/CU x 8 waves = 16 waves/CU (cap 50%).
//  - Split-wait pipeline kept: Us(2) then Vs(2); vmcnt(2)+barrier -> S-MFMA
//    while Vs in flight; vmcnt(0)+barrier -> PV. exp2 softmax, setprio.
// In-place y into v is race-free: block reads only its own q-slice of v.
// ---------------------------------------------------------------------------
#define LOG2E 1.44269504f

__global__ __launch_bounds__(512)
void flash_attn(const u16* __restrict__ v, const u16* __restrict__ U,
                const u16* __restrict__ vT, const float* __restrict__ bc,
                u16* __restrict__ y) {
    __shared__ alignas(16) u16 Us[128 * 64];    // [key][chunk^key&7] (swizzled)
    __shared__ alignas(16) u16 Vs[64 * 128];    // [dim][chunk^dim&15] (swizzled)
    __shared__ alignas(16) u16 Ps[128 * 136];   // q x keys, stride 136
    __shared__ u16 bcs[Tz];                     // bf16(bc * log2e)

    // grid remap: 768 = 8 xcd x 96 slots; xcd-affine columns, heavy qi first
    const int bi = blockIdx.x;
    const int xcd = bi & 7;
    const int slot = bi >> 3;                   // 0..95
    const int col = (slot % 12) * 8 + xcd;      // 0..95, col%8 == xcd
    const int qi = 7 - slot / 12;               // 0..7, heavy tiles first
    const int b = col / NHz, h = col % NHz;

    const int tid = threadIdx.x, lane = tid & 63, w = tid >> 6;
    const int quad = lane >> 4, cl = lane & 15;
    const int q0 = qi * 128;
    const int wrow = w * 16;                    // wave's 16 q-rows (w 0..7)

    for (int j = tid; j < Tz; j += 512) bcs[j] = f2bf(bc[j] * LOG2E);

    // resident A-fragments of vq (this block's own 128x64 slice)
    const u16* vq = v + ((long long)b * Tz + q0) * Cz + h * HDz;
    bf16x8 aS[2];
#pragma unroll
    for (int ks = 0; ks < 2; ks++)
        aS[ks] = *(const bf16x8*)(vq + (long long)(wrow + cl) * Cz + ks * 32 + quad * 8);

    f32x4 Oacc[4] = {};
    float mrow[4], lrow[4];
#pragma unroll
    for (int r = 0; r < 4; r++) { mrow[r] = -3.0e38f; lrow[r] = 0.f; }

    const u16* Ub = U + (long long)b * Tz * Cz + h * HDz;
    const u16* Vb = vT + ((long long)b * Cz + h * HDz) * Tz;

    __syncthreads();   // bcs visible; drains pre-loop VMEM

    const int kts = qi + 1;   // # of 128-wide k-tiles covering [0, q0+128)
    for (int kt = 0; kt < kts; kt++) {
        if (kt) __builtin_amdgcn_s_barrier();   // WAR: all waves done with Us/Vs
        const u16* Ug = Ub + (long long)kt * 128 * Cz;
#pragma unroll
        for (int i = 0; i < 2; i++) {           // Us first (waited by vmcnt(2))
            int e = (i * 512 + tid) * 8;
            int key = e >> 6;
            int ch = ((e & 63) >> 3) ^ (key & 7);   // global-side swizzle
            __builtin_amdgcn_global_load_lds(
                (const __attribute__((address_space(1))) uint32_t*)(Ug + (long long)key * Cz + ch * 8),
                (__attribute__((address_space(3))) uint32_t*)(Us + e), 16, 0, 0);
        }
        const u16* Vg = Vb + kt * 128;
#pragma unroll
        for (int i = 0; i < 2; i++) {           // Vs second (stays in flight)
            int e = (i * 512 + tid) * 8;
            int dim = e >> 7;
            int ch = ((e & 127) >> 3) ^ (dim & 15);  // global-side swizzle
            __builtin_amdgcn_global_load_lds(
                (const __attribute__((address_space(1))) uint32_t*)(Vg + (long long)dim * Tz + ch * 8),
                (__attribute__((address_space(3))) uint32_t*)(Vs + e), 16, 0, 0);
        }
        // own Us landed (in-order retire); Vs (newest 2) may still be in flight
        asm volatile("s_waitcnt vmcnt(2)" ::: "memory");
        __builtin_amdgcn_s_barrier();           // all waves' Us landed

        // S = vq . Uk^T  (wave tile 16 x 128) — overlaps Vs flight time
        f32x4 S[8] = {};
        __builtin_amdgcn_s_setprio(1);
#pragma unroll
        for (int ks = 0; ks < 2; ks++)
#pragma unroll
            for (int nt = 0; nt < 8; nt++) {
                int key = nt * 16 + cl;
                bf16x8 bS = *(const bf16x8*)&Us[key * 64 + (((ks * 4 + quad) ^ (key & 7)) * 8)];
                S[nt] = __builtin_amdgcn_mfma_f32_16x16x32_bf16(aS[ks], bS, S[nt], 0, 0, 0);
            }
        __builtin_amdgcn_s_setprio(0);

        const bool last = (kt == kts - 1);
#pragma unroll
        for (int nt = 0; nt < 8; nt++) {
            float bl = bf2f(bcs[kt * 128 + nt * 16 + cl]);
#pragma unroll
            for (int r = 0; r < 4; r++) {
                int rowg = q0 + wrow + quad * 4 + r;
                int colg = kt * 128 + nt * 16 + cl;
                // log2 domain: s2 = S*(0.125*log2e) + bc*log2e
                float s = S[nt][r] * (0.125f * LOG2E) + bl;
                if (last && colg > rowg) s = -3.0e38f;
                S[nt][r] = s;
            }
        }

        // row max (regs, then across the 16 lanes of the quad group)
        float mnew[4], alpha[4];
#pragma unroll
        for (int r = 0; r < 4; r++) {
            float m = S[0][r];
#pragma unroll
            for (int nt = 1; nt < 8; nt++) m = fmaxf(m, S[nt][r]);
#pragma unroll
            for (int d = 1; d < 16; d <<= 1) m = fmaxf(m, __shfl_xor(m, d));
            mnew[r] = fmaxf(mrow[r], m);
            alpha[r] = __builtin_amdgcn_exp2f(mrow[r] - mnew[r]);
            mrow[r] = mnew[r];
        }

        // P = exp2(S - m) -> LDS (wave-private rows), accumulate row sums
        float psum[4] = {};
#pragma unroll
        for (int nt = 0; nt < 8; nt++)
#pragma unroll
            for (int r = 0; r < 4; r++) {
                float p = __builtin_amdgcn_exp2f(S[nt][r] - mnew[r]);
                psum[r] += p;
                Ps[(wrow + quad * 4 + r) * 136 + nt * 16 + cl] = f2bf(p);
            }
#pragma unroll
        for (int r = 0; r < 4; r++) {
            float s = psum[r];
#pragma unroll
            for (int d = 1; d < 16; d <<= 1) s += __shfl_xor(s, d);
            lrow[r] = lrow[r] * alpha[r] + s;
#pragma unroll
            for (int nt2 = 0; nt2 < 4; nt2++)
                Oacc[nt2][r] *= alpha[r];
        }

        // own Vs landed; barrier -> all waves' Vs landed
        asm volatile("s_waitcnt vmcnt(0)" ::: "memory");
        __builtin_amdgcn_s_barrier();

        // O += P . Vk   (K = 128)
        __builtin_amdgcn_s_setprio(1);
#pragma unroll
        for (int ks = 0; ks < 4; ks++) {
            bf16x8 pA = *(const bf16x8*)&Ps[(wrow + cl) * 136 + ks * 32 + quad * 8];
#pragma unroll
            for (int nt2 = 0; nt2 < 4; nt2++) {
                int dim = nt2 * 16 + cl;
                bf16x8 vB = *(const bf16x8*)&Vs[dim * 128 + (((ks * 4 + quad) ^ cl) * 8)];
                Oacc[nt2] = __builtin_amdgcn_mfma_f32_16x16x32_bf16(pA, vB, Oacc[nt2], 0, 0, 0);
            }
        }
        __builtin_amdgcn_s_setprio(0);
    }

    // epilogue: O /= l, write y (in-place into v's own region)
    u16* yq = y + ((long long)b * Tz + q0) * Cz + h * HDz;
#pragma unroll
    for (int r = 0; r < 4; r++) {
        float inv = 1.f / lrow[r];
#pragma unroll
        for (int nt2 = 0; nt2 < 4; nt2++)
            yq[(long long)(wrow + quad * 4 + r) * Cz + nt2 * 16 + cl] =
                f2bf(Oacc[nt2][r] * inv);
    }
}

// ---------------------------------------------------------------------------
extern "C" void kernel_launch(void* const* d_in, const int* in_sizes, int n_in,
                              void* d_out, int out_size, void* d_ws, size_t ws_size,
                              hipStream_t stream) {
    const float* x  = (const float*)d_in[0];
    const float* Wv = (const float*)d_in[1];
    const float* bv = (const float*)d_in[2];
    const float* Wl = (const float*)d_in[3];
    const float* Wc = (const float*)d_in[4];
    const float* bc = (const float*)d_in[5];
    const float* Wp = (const float*)d_in[6];
    const float* bp = (const float*)d_in[7];

    // ws (bf16 elems, ~59 MB): xb, Wvb, Wcb, Wpb, WlT, Wcl, vbf, vT, U
    u16* ws  = (u16*)d_ws;
    u16* xb  = ws;
    u16* Wvb = xb  + (size_t)Bz * Tz * Cz;
    u16* Wcb = Wvb + (size_t)Cz * Cz;
    u16* Wpb = Wcb + (size_t)Tz * Tz;
    u16* WlT = Wpb + (size_t)Cz * Cz;
    u16* Wcl = WlT + (size_t)Tz * Tz;
    u16* vbf = Wcl + (size_t)Tz * Tz;
    u16* vT  = vbf + (size_t)Bz * Tz * Cz;
    u16* U   = vT  + (size_t)Bz * Tz * Cz;

    const long long sTC = (long long)Tz * Cz;
    const long long sCT = (long long)Cz * Tz;

    // 0) one-time bf16 conversions (single fused launch)
    cvt_all<<<(N4_ALL + 255) / 256, 256, 0, stream>>>(x, Wv, Wc, Wp, xb, Wvb, Wcb, Wpb);
    // 1) WlT = Wl^T (fp32 -> bf16)
    transpose_to_bf16<true><<<dim3(32, 32, 1), dim3(32, 8), 0, stream>>>(Wl, WlT, Tz, Tz, 0, 0);
    // 2) Wcl = Wcb . WlT^T = Wc @ Wl — 64^2 tile: 256 blocks = 1/CU
    gemm_bt<64, 64, 1, 1, false, false><<<dim3(Tz / 64, Tz / 64, 1), 64, 0, stream>>>(
        Wcb, 0, Tz, WlT, 0, Tz, Wcl, 0, Tz, nullptr, Tz, 1.f);
    // 3) v = xb . Wvb^T + bv — 64x128 tile: 768 blocks = 3/CU (was 384 = 1.5)
    gemm_bt<64, 128, 1, 2, false, true><<<dim3(Cz / 128, (Bz * Tz) / 64, 1), 128, 0, stream>>>(
        xb, 0, Cz, Wvb, 0, Cz, vbf, 0, Cz, bv, Cz, 1.f);
    // 4) vT[b] = v[b]^T
    transpose_to_bf16<false><<<dim3(Cz / 32, Tz / 32, Bz), dim3(32, 8), 0, stream>>>(
        vbf, vT, Tz, Cz, sTC, sCT);
    // 5) U[b] = Wcl @ v[b]  (= Wcl . vT[b]^T), K=T — 64x128 tile
    gemm_bt<64, 128, 1, 2, false, false><<<dim3(Cz / 128, Tz / 64, Bz), 128, 0, stream>>>(
        Wcl, 0, Tz, vT, sCT, Tz, U, sTC, Cz, nullptr, Tz, 1.f);
    // 6) fused logits -> causal softmax -> P.V, y in-place into vbf
    flash_attn<<<dim3(8 * NHz * Bz, 1, 1), 512, 0, stream>>>(vbf, U, vT, bc, vbf);
    // 7) out = y . Wpb^T + bp  (fp32 out) — 64x128 tile
    gemm_bt<64, 128, 1, 2, true, true><<<dim3(Cz / 128, (Bz * Tz) / 64, 1), 128, 0, stream>>>(
        vbf, 0, Cz, Wpb, 0, Cz, (float*)d_out, 0, Cz, bp, Cz, 1.f);
}

// Round 10
// 234.194 us; speedup vs baseline: 1.1268x; 1.0061x over previous
//
#include <hip/hip_runtime.h>
#include <stdint.h>

#define Bz 8
#define Tz 1024
#define Cz 768
#define NHz 12
#define HDz 64

typedef unsigned short u16;
typedef __attribute__((ext_vector_type(8))) __bf16 bf16x8;
typedef __attribute__((ext_vector_type(4))) float f32x4;
typedef __attribute__((ext_vector_type(4))) unsigned int u32x4;

__device__ __forceinline__ float bf2f(u16 b) {
    union { uint32_t u; float f; } c; c.u = ((uint32_t)b) << 16; return c.f;
}
__device__ __forceinline__ u16 f2bf(float f) {
    union { float f; uint32_t u; } c; c.f = f;
    uint32_t u = c.u;
    return (u16)((u + 0x7fffu + ((u >> 16) & 1u)) >> 16);
}

// ---------------------------------------------------------------------------
// Fused fp32 -> bf16 elementwise convert for all 4 input tensors (1 launch).
// ---------------------------------------------------------------------------
#define N4_X  (Bz * Tz * Cz / 4)
#define N4_WV (Cz * Cz / 4)
#define N4_WC (Tz * Tz / 4)
#define N4_WP (Cz * Cz / 4)
#define N4_ALL (N4_X + N4_WV + N4_WC + N4_WP)

__global__ __launch_bounds__(256)
void cvt_all(const float* __restrict__ x, const float* __restrict__ wv,
             const float* __restrict__ wc, const float* __restrict__ wp,
             u16* __restrict__ xb, u16* __restrict__ wvb,
             u16* __restrict__ wcb, u16* __restrict__ wpb) {
    int i = blockIdx.x * 256 + threadIdx.x;
    if (i >= N4_ALL) return;
    const float* in;
    u16* out;
    if (i < N4_X) {
        in = x; out = xb;
    } else if (i < N4_X + N4_WV) {
        in = wv; out = wvb; i -= N4_X;
    } else if (i < N4_X + N4_WV + N4_WC) {
        in = wc; out = wcb; i -= N4_X + N4_WV;
    } else {
        in = wp; out = wpb; i -= N4_X + N4_WV + N4_WC;
    }
    float4 v = ((const float4*)in)[i];
    union { u16 h[4]; uint2 u; } o;
    o.h[0] = f2bf(v.x); o.h[1] = f2bf(v.y); o.h[2] = f2bf(v.z); o.h[3] = f2bf(v.w);
    ((uint2*)out)[i] = o.u;
}

// ---------------------------------------------------------------------------
// C = alpha * (A . B^T) [+ bias_col]   MFMA 16x16x32, all-bf16 operands.
// Single-barrier double-buffered K-loop (2-phase).
// v6 POST-MORTEM: 64x128 retile regressed ~5.5us net (staging bytes/FLOP
// +50% not paid back) -> steps 3/5/7 reverted to 128^2 (v5 measured-best).
// ---------------------------------------------------------------------------
template<int BM, int BN, int WM, int WN, bool OUTF32, bool HASBIAS>
__global__ __launch_bounds__(WM * WN * 64)
void gemm_bt(const u16* __restrict__ A, long long sAz, int lda,
             const u16* __restrict__ Bp, long long sBz, int ldb,
             void* __restrict__ Cp, long long sCz, int ldc,
             const float* __restrict__ bias, int K, float alpha) {
    constexpr int NT = WM * WN * 64;
    constexpr int BK = 32;
    constexpr int AI = (BM * BK) / (NT * 8);
    constexpr int BI = (BN * BK) / (NT * 8);
    static_assert(AI >= 1 && (BM * BK) % (NT * 8) == 0, "A staging");
    static_assert(BI >= 1 && (BN * BK) % (NT * 8) == 0, "B staging");
    static_assert(BM == WM * 64 && BN == WN * 64, "wave tiling");

    __shared__ alignas(16) u16 As[2][BM * BK];
    __shared__ alignas(16) u16 Bs[2][BN * BK];

    const int z = blockIdx.z;
    const u16* Ag = A + (long long)z * sAz;
    const u16* Bg = Bp + (long long)z * sBz;

    const int tid = threadIdx.x;
    const int lane = tid & 63;
    const int w = tid >> 6;
    const int wm = w / WN;
    const int wn = w % WN;
    const int rowBase = blockIdx.y * BM;
    const int colBase = blockIdx.x * BN;
    const int koff = (lane >> 4) * 8;
    const int frow = lane & 15;

    auto stage = [&](int buf, int k0) {
#pragma unroll
        for (int i = 0; i < AI; i++) {
            int e = (i * NT + tid) * 8;
            const u16* g = Ag + (long long)(rowBase + (e >> 5)) * lda + k0 + (e & 31);
            __builtin_amdgcn_global_load_lds(
                (const __attribute__((address_space(1))) uint32_t*)g,
                (__attribute__((address_space(3))) uint32_t*)(&As[buf][0] + e), 16, 0, 0);
        }
#pragma unroll
        for (int i = 0; i < BI; i++) {
            int e = (i * NT + tid) * 8;
            const u16* g = Bg + (long long)(colBase + (e >> 5)) * ldb + k0 + (e & 31);
            __builtin_amdgcn_global_load_lds(
                (const __attribute__((address_space(1))) uint32_t*)g,
                (__attribute__((address_space(3))) uint32_t*)(&Bs[buf][0] + e), 16, 0, 0);
        }
    };

    f32x4 acc[4][4] = {};

    const int nk = K / BK;
    stage(0, 0);
    __syncthreads();

#pragma unroll 1
    for (int t = 0; t < nk; ++t) {
        const int cur = t & 1;
        if (t + 1 < nk) stage(cur ^ 1, (t + 1) * BK);

        bf16x8 af[4], bfr[4];
#pragma unroll
        for (int mt = 0; mt < 4; mt++)
            af[mt] = *(const bf16x8*)&As[cur][(wm * 64 + mt * 16 + frow) * BK + koff];
#pragma unroll
        for (int nt = 0; nt < 4; nt++)
            bfr[nt] = *(const bf16x8*)&Bs[cur][(wn * 64 + nt * 16 + frow) * BK + koff];
#pragma unroll
        for (int mt = 0; mt < 4; mt++)
#pragma unroll
            for (int nt = 0; nt < 4; nt++)
                acc[mt][nt] = __builtin_amdgcn_mfma_f32_16x16x32_bf16(
                    af[mt], bfr[nt], acc[mt][nt], 0, 0, 0);

        __syncthreads();
    }

    const int r0 = rowBase + wm * 64;
    const int c0 = colBase + wn * 64;
    const int rl = (lane >> 4) * 4;
    const int cl = lane & 15;
#pragma unroll
    for (int mt = 0; mt < 4; mt++) {
#pragma unroll
        for (int nt = 0; nt < 4; nt++) {
#pragma unroll
            for (int r = 0; r < 4; r++) {
                int row = r0 + mt * 16 + rl + r;
                int col = c0 + nt * 16 + cl;
                float v = acc[mt][nt][r] * alpha;
                if (HASBIAS) v += bias[col];
                if (OUTF32)
                    ((float*)Cp)[(long long)z * sCz + (long long)row * ldc + col] = v;
                else
                    ((u16*)Cp)[(long long)z * sCz + (long long)row * ldc + col] = f2bf(v);
            }
        }
    }
}

// ---------------------------------------------------------------------------
// Transpose to bf16: in [rows,cols] (fp32 if INF32 else bf16) -> [cols,rows].
// ---------------------------------------------------------------------------
template<bool INF32>
__global__ __launch_bounds__(256)
void transpose_to_bf16(const void* __restrict__ in, u16* __restrict__ out,
                       int rows, int cols, long long sInZ, long long sOutZ) {
    __shared__ u16 tile[32][33];
    const int z = blockIdx.z;
    const int c0 = blockIdx.x * 32, r0 = blockIdx.y * 32;
    const int tx = threadIdx.x, ty = threadIdx.y;
#pragma unroll
    for (int i = 0; i < 32; i += 8) {
        long long off = (long long)z * sInZ + (long long)(r0 + ty + i) * cols + c0 + tx;
        tile[ty + i][tx] = INF32 ? f2bf(((const float*)in)[off]) : ((const u16*)in)[off];
    }
    __syncthreads();
#pragma unroll
    for (int i = 0; i < 32; i += 8)
        out[(long long)z * sOutZ + (long long)(c0 + ty + i) * rows + r0 + tx] = tile[tx][ty + i];
}

// ---------------------------------------------------------------------------
// Fused flash attention v7: T14 async-stage for Us.
//  - v6 measured 47.1us, MfmaUtil 11.5: the per-iter stall is the Us fetch
//    latency exposed at vmcnt right after issue (~200-900cy each iter).
//  - v7: Us(t+1) prefetched into REGISTERS (2 x uint4/thread) right after
//    S-MFMA(t); latency hides under softmax+PV. Post-PV barrier -> vmcnt(0)
//    -> ds_write Us(t+1) -> gload_lds Vs(t+1) -> lgkmcnt(0)+barrier.
//    Pre-PV vmcnt(pf?2:0) waits exactly the Vs pair (in-order retire),
//    issued a full iteration earlier -> fully hidden.
//  - 3 uniform raw barriers/iter; Us WAR safe (overwrite only after the
//    all-wave post-PV barrier); lgkmcnt(0) before the visibility barrier.
//  - exp2 softmax, setprio, XCD-affine remap unchanged. LDS 69632 B.
// In-place y into v is race-free: block reads only its own q-slice of v.
// ---------------------------------------------------------------------------
#define LOG2E 1.44269504f

__global__ __launch_bounds__(512)
void flash_attn(const u16* __restrict__ v, const u16* __restrict__ U,
                const u16* __restrict__ vT, const float* __restrict__ bc,
                u16* __restrict__ y) {
    __shared__ alignas(16) u16 Us[128 * 64];    // [key][chunk^key&7] (swizzled)
    __shared__ alignas(16) u16 Vs[64 * 128];    // [dim][chunk^dim&15] (swizzled)
    __shared__ alignas(16) u16 Ps[128 * 136];   // q x keys, stride 136
    __shared__ u16 bcs[Tz];                     // bf16(bc * log2e)

    // grid remap: 768 = 8 xcd x 96 slots; xcd-affine columns, heavy qi first
    const int bi = blockIdx.x;
    const int xcd = bi & 7;
    const int slot = bi >> 3;                   // 0..95
    const int col = (slot % 12) * 8 + xcd;      // 0..95, col%8 == xcd
    const int qi = 7 - slot / 12;               // 0..7, heavy tiles first
    const int b = col / NHz, h = col % NHz;

    const int tid = threadIdx.x, lane = tid & 63, w = tid >> 6;
    const int quad = lane >> 4, cl = lane & 15;
    const int q0 = qi * 128;
    const int wrow = w * 16;                    // wave's 16 q-rows (w 0..7)

    for (int j = tid; j < Tz; j += 512) bcs[j] = f2bf(bc[j] * LOG2E);

    // resident A-fragments of vq (this block's own 128x64 slice)
    const u16* vq = v + ((long long)b * Tz + q0) * Cz + h * HDz;
    bf16x8 aS[2];
#pragma unroll
    for (int ks = 0; ks < 2; ks++)
        aS[ks] = *(const bf16x8*)(vq + (long long)(wrow + cl) * Cz + ks * 32 + quad * 8);

    f32x4 Oacc[4] = {};
    float mrow[4], lrow[4];
#pragma unroll
    for (int r = 0; r < 4; r++) { mrow[r] = -3.0e38f; lrow[r] = 0.f; }

    const u16* Ub = U + (long long)b * Tz * Cz + h * HDz;
    const u16* Vb = vT + ((long long)b * Cz + h * HDz) * Tz;

    // per-thread staging geometry (shared by gload_lds and reg paths)
    const int e0 = tid * 8;                     // i=0 element offset
    const int e1 = (512 + tid) * 8;             // i=1
    const int ukey0 = e0 >> 6, uch0 = ((e0 & 63) >> 3) ^ (ukey0 & 7);
    const int ukey1 = e1 >> 6, uch1 = ((e1 & 63) >> 3) ^ (ukey1 & 7);
    const int vdim0 = e0 >> 7, vch0 = ((e0 & 127) >> 3) ^ (vdim0 & 15);
    const int vdim1 = e1 >> 7, vch1 = ((e1 & 127) >> 3) ^ (vdim1 & 15);

    __syncthreads();   // bcs visible; drains pre-loop VMEM

    const int kts = qi + 1;   // # of 128-wide k-tiles covering [0, q0+128)

    // prologue: stage tile 0 (Us + Vs) and drain
    {
        const u16* Ug = Ub;
        __builtin_amdgcn_global_load_lds(
            (const __attribute__((address_space(1))) uint32_t*)(Ug + (long long)ukey0 * Cz + uch0 * 8),
            (__attribute__((address_space(3))) uint32_t*)(Us + e0), 16, 0, 0);
        __builtin_amdgcn_global_load_lds(
            (const __attribute__((address_space(1))) uint32_t*)(Ug + (long long)ukey1 * Cz + uch1 * 8),
            (__attribute__((address_space(3))) uint32_t*)(Us + e1), 16, 0, 0);
        const u16* Vg = Vb;
        __builtin_amdgcn_global_load_lds(
            (const __attribute__((address_space(1))) uint32_t*)(Vg + (long long)vdim0 * Tz + vch0 * 8),
            (__attribute__((address_space(3))) uint32_t*)(Vs + e0), 16, 0, 0);
        __builtin_amdgcn_global_load_lds(
            (const __attribute__((address_space(1))) uint32_t*)(Vg + (long long)vdim1 * Tz + vch1 * 8),
            (__attribute__((address_space(3))) uint32_t*)(Vs + e1), 16, 0, 0);
        asm volatile("s_waitcnt vmcnt(0)" ::: "memory");
        __builtin_amdgcn_s_barrier();
    }

#pragma unroll 1
    for (int kt = 0; kt < kts; kt++) {
        const bool pf = (kt + 1 < kts);

        // S = vq . Uk^T  (wave tile 16 x 128)
        f32x4 S[8] = {};
        __builtin_amdgcn_s_setprio(1);
#pragma unroll
        for (int ks = 0; ks < 2; ks++)
#pragma unroll
            for (int nt = 0; nt < 8; nt++) {
                int key = nt * 16 + cl;
                bf16x8 bS = *(const bf16x8*)&Us[key * 64 + (((ks * 4 + quad) ^ (key & 7)) * 8)];
                S[nt] = __builtin_amdgcn_mfma_f32_16x16x32_bf16(aS[ks], bS, S[nt], 0, 0, 0);
            }
        __builtin_amdgcn_s_setprio(0);

        // prefetch Us(kt+1) -> regs; latency hides under softmax+PV
        u32x4 u0, u1;
        if (pf) {
            const u16* Ug = Ub + (long long)(kt + 1) * 128 * Cz;
            u0 = *(const u32x4*)(Ug + (long long)ukey0 * Cz + uch0 * 8);
            u1 = *(const u32x4*)(Ug + (long long)ukey1 * Cz + uch1 * 8);
        }

        const bool last = (kt == kts - 1);
#pragma unroll
        for (int nt = 0; nt < 8; nt++) {
            float bl = bf2f(bcs[kt * 128 + nt * 16 + cl]);
#pragma unroll
            for (int r = 0; r < 4; r++) {
                int rowg = q0 + wrow + quad * 4 + r;
                int colg = kt * 128 + nt * 16 + cl;
                float s = S[nt][r] * (0.125f * LOG2E) + bl;
                if (last && colg > rowg) s = -3.0e38f;
                S[nt][r] = s;
            }
        }

        // row max (regs, then across the 16 lanes of the quad group)
        float mnew[4], alpha[4];
#pragma unroll
        for (int r = 0; r < 4; r++) {
            float m = S[0][r];
#pragma unroll
            for (int nt = 1; nt < 8; nt++) m = fmaxf(m, S[nt][r]);
#pragma unroll
            for (int d = 1; d < 16; d <<= 1) m = fmaxf(m, __shfl_xor(m, d));
            mnew[r] = fmaxf(mrow[r], m);
            alpha[r] = __builtin_amdgcn_exp2f(mrow[r] - mnew[r]);
            mrow[r] = mnew[r];
        }

        // P = exp2(S - m) -> LDS (wave-private rows), accumulate row sums
        float psum[4] = {};
#pragma unroll
        for (int nt = 0; nt < 8; nt++)
#pragma unroll
            for (int r = 0; r < 4; r++) {
                float p = __builtin_amdgcn_exp2f(S[nt][r] - mnew[r]);
                psum[r] += p;
                Ps[(wrow + quad * 4 + r) * 136 + nt * 16 + cl] = f2bf(p);
            }
#pragma unroll
        for (int r = 0; r < 4; r++) {
            float s = psum[r];
#pragma unroll
            for (int d = 1; d < 16; d <<= 1) s += __shfl_xor(s, d);
            lrow[r] = lrow[r] * alpha[r] + s;
#pragma unroll
            for (int nt2 = 0; nt2 < 4; nt2++)
                Oacc[nt2][r] *= alpha[r];
        }

        // Vs(kt) ready: for kt>=1 wait the Vs pair (oldest outstanding);
        // uReg (newest 2, if pf) stays in flight. kt==0: Vs from prologue.
        if (kt) {
            if (pf) asm volatile("s_waitcnt vmcnt(2)" ::: "memory");
            else    asm volatile("s_waitcnt vmcnt(0)" ::: "memory");
            __builtin_amdgcn_s_barrier();       // all waves' Vs landed
        }

        // O += P . Vk   (K = 128)
        __builtin_amdgcn_s_setprio(1);
#pragma unroll
        for (int ks = 0; ks < 4; ks++) {
            bf16x8 pA = *(const bf16x8*)&Ps[(wrow + cl) * 136 + ks * 32 + quad * 8];
#pragma unroll
            for (int nt2 = 0; nt2 < 4; nt2++) {
                int dim = nt2 * 16 + cl;
                bf16x8 vB = *(const bf16x8*)&Vs[dim * 128 + (((ks * 4 + quad) ^ cl) * 8)];
                Oacc[nt2] = __builtin_amdgcn_mfma_f32_16x16x32_bf16(pA, vB, Oacc[nt2], 0, 0, 0);
            }
        }
        __builtin_amdgcn_s_setprio(0);

        if (pf) {
            __builtin_amdgcn_s_barrier();       // all waves done reading Us/Vs(kt)
            asm volatile("s_waitcnt vmcnt(0)" ::: "memory");   // uReg landed
            *(u32x4*)(Us + e0) = u0;            // ds_write Us(kt+1)
            *(u32x4*)(Us + e1) = u1;
            const u16* Vg = Vb + (kt + 1) * 128;
            __builtin_amdgcn_global_load_lds(
                (const __attribute__((address_space(1))) uint32_t*)(Vg + (long long)vdim0 * Tz + vch0 * 8),
                (__attribute__((address_space(3))) uint32_t*)(Vs + e0), 16, 0, 0);
            __builtin_amdgcn_global_load_lds(
                (const __attribute__((address_space(1))) uint32_t*)(Vg + (long long)vdim1 * Tz + vch1 * 8),
                (__attribute__((address_space(3))) uint32_t*)(Vs + e1), 16, 0, 0);
            asm volatile("s_waitcnt lgkmcnt(0)" ::: "memory"); // Us writes retired
            __builtin_amdgcn_s_barrier();       // Us(kt+1) visible to all
        }
    }

    // epilogue: O /= l, write y (in-place into v's own region)
    u16* yq = y + ((long long)b * Tz + q0) * Cz + h * HDz;
#pragma unroll
    for (int r = 0; r < 4; r++) {
        float inv = 1.f / lrow[r];
#pragma unroll
        for (int nt2 = 0; nt2 < 4; nt2++)
            yq[(long long)(wrow + quad * 4 + r) * Cz + nt2 * 16 + cl] =
                f2bf(Oacc[nt2][r] * inv);
    }
}

// ---------------------------------------------------------------------------
extern "C" void kernel_launch(void* const* d_in, const int* in_sizes, int n_in,
                              void* d_out, int out_size, void* d_ws, size_t ws_size,
                              hipStream_t stream) {
    const float* x  = (const float*)d_in[0];
    const float* Wv = (const float*)d_in[1];
    const float* bv = (const float*)d_in[2];
    const float* Wl = (const float*)d_in[3];
    const float* Wc = (const float*)d_in[4];
    const float* bc = (const float*)d_in[5];
    const float* Wp = (const float*)d_in[6];
    const float* bp = (const float*)d_in[7];

    // ws (bf16 elems, ~59 MB): xb, Wvb, Wcb, Wpb, WlT, Wcl, vbf, vT, U
    u16* ws  = (u16*)d_ws;
    u16* xb  = ws;
    u16* Wvb = xb  + (size_t)Bz * Tz * Cz;
    u16* Wcb = Wvb + (size_t)Cz * Cz;
    u16* Wpb = Wcb + (size_t)Tz * Tz;
    u16* WlT = Wpb + (size_t)Cz * Cz;
    u16* Wcl = WlT + (size_t)Tz * Tz;
    u16* vbf = Wcl + (size_t)Tz * Tz;
    u16* vT  = vbf + (size_t)Bz * Tz * Cz;
    u16* U   = vT  + (size_t)Bz * Tz * Cz;

    const long long sTC = (long long)Tz * Cz;
    const long long sCT = (long long)Cz * Tz;

    // 0) one-time bf16 conversions (single fused launch)
    cvt_all<<<(N4_ALL + 255) / 256, 256, 0, stream>>>(x, Wv, Wc, Wp, xb, Wvb, Wcb, Wpb);
    // 1) WlT = Wl^T (fp32 -> bf16)
    transpose_to_bf16<true><<<dim3(32, 32, 1), dim3(32, 8), 0, stream>>>(Wl, WlT, Tz, Tz, 0, 0);
    // 2) Wcl = Wcb . WlT^T = Wc @ Wl — 64^2 tile: 256 blocks = 1/CU
    gemm_bt<64, 64, 1, 1, false, false><<<dim3(Tz / 64, Tz / 64, 1), 64, 0, stream>>>(
        Wcb, 0, Tz, WlT, 0, Tz, Wcl, 0, Tz, nullptr, Tz, 1.f);
    // 3) v = xb . Wvb^T + bv — 128^2 (reverted; 64x128 measured worse)
    gemm_bt<128, 128, 2, 2, false, true><<<dim3(Cz / 128, (Bz * Tz) / 128, 1), 256, 0, stream>>>(
        xb, 0, Cz, Wvb, 0, Cz, vbf, 0, Cz, bv, Cz, 1.f);
    // 4) vT[b] = v[b]^T
    transpose_to_bf16<false><<<dim3(Cz / 32, Tz / 32, Bz), dim3(32, 8), 0, stream>>>(
        vbf, vT, Tz, Cz, sTC, sCT);
    // 5) U[b] = Wcl @ v[b]  (= Wcl . vT[b]^T), K=T — 128^2 (reverted)
    gemm_bt<128, 128, 2, 2, false, false><<<dim3(Cz / 128, Tz / 128, Bz), 256, 0, stream>>>(
        Wcl, 0, Tz, vT, sCT, Tz, U, sTC, Cz, nullptr, Tz, 1.f);
    // 6) fused logits -> causal softmax -> P.V, y in-place into vbf
    flash_attn<<<dim3(8 * NHz * Bz, 1, 1), 512, 0, stream>>>(vbf, U, vT, bc, vbf);
    // 7) out = y . Wpb^T + bp  (fp32 out) — 128^2 (reverted)
    gemm_bt<128, 128, 2, 2, true, true><<<dim3(Cz / 128, (Bz * Tz) / 128, 1), 256, 0, stream>>>(
        vbf, 0, Cz, Wpb, 0, Cz, (float*)d_out, 0, Cz, bp, Cz, 1.f);
}

// Round 12
// 221.301 us; speedup vs baseline: 1.1925x; 1.0583x over previous
//
#include <hip/hip_runtime.h>
#include <stdint.h>

#define Bz 8
#define Tz 1024
#define Cz 768
#define NHz 12
#define HDz 64

typedef unsigned short u16;
typedef __attribute__((ext_vector_type(8))) __bf16 bf16x8;
typedef __attribute__((ext_vector_type(4))) float f32x4;
typedef __attribute__((ext_vector_type(4))) unsigned int u32x4;

__device__ __forceinline__ float bf2f(u16 b) {
    union { uint32_t u; float f; } c; c.u = ((uint32_t)b) << 16; return c.f;
}
__device__ __forceinline__ u16 f2bf(float f) {
    union { float f; uint32_t u; } c; c.f = f;
    uint32_t u = c.u;
    return (u16)((u + 0x7fffu + ((u >> 16) & 1u)) >> 16);
}
__device__ __forceinline__ u16 f2bf_hw(float f) {   // native RTNE cast (v_cvt_pk)
    __bf16 b = (__bf16)f;
    union { __bf16 b; u16 u; } c; c.b = b; return c.u;
}

// ---------------------------------------------------------------------------
// Fused fp32 -> bf16 elementwise convert for all 4 input tensors (1 launch).
// ---------------------------------------------------------------------------
#define N4_X  (Bz * Tz * Cz / 4)
#define N4_WV (Cz * Cz / 4)
#define N4_WC (Tz * Tz / 4)
#define N4_WP (Cz * Cz / 4)
#define N4_ALL (N4_X + N4_WV + N4_WC + N4_WP)

__global__ __launch_bounds__(256)
void cvt_all(const float* __restrict__ x, const float* __restrict__ wv,
             const float* __restrict__ wc, const float* __restrict__ wp,
             u16* __restrict__ xb, u16* __restrict__ wvb,
             u16* __restrict__ wcb, u16* __restrict__ wpb) {
    int i = blockIdx.x * 256 + threadIdx.x;
    if (i >= N4_ALL) return;
    const float* in;
    u16* out;
    if (i < N4_X) {
        in = x; out = xb;
    } else if (i < N4_X + N4_WV) {
        in = wv; out = wvb; i -= N4_X;
    } else if (i < N4_X + N4_WV + N4_WC) {
        in = wc; out = wcb; i -= N4_X + N4_WV;
    } else {
        in = wp; out = wpb; i -= N4_X + N4_WV + N4_WC;
    }
    float4 v = ((const float4*)in)[i];
    union { u16 h[4]; uint2 u; } o;
    o.h[0] = f2bf(v.x); o.h[1] = f2bf(v.y); o.h[2] = f2bf(v.z); o.h[3] = f2bf(v.w);
    ((uint2*)out)[i] = o.u;
}

// ---------------------------------------------------------------------------
// C = alpha * (A . B^T) [+ bias_col]   MFMA 16x16x32, all-bf16 operands.
// BK=64, 2-phase dbuf: barriers per K halved vs BK=32 (32 MFMA/barrier).
// GEMMs here are GRID-capped (1.5 blocks/CU), so 64KB LDS costs nothing.
// BK=64 row stride (128B) is bank-degenerate -> A/B staged with the
// flash-proven global-source chunk XOR swizzle (ch ^= row&7); readers
// XOR back -> full 32-bank spread on ds_read_b128.
// ---------------------------------------------------------------------------
template<int BM, int BN, int WM, int WN, bool OUTF32, bool HASBIAS>
__global__ __launch_bounds__(WM * WN * 64)
void gemm_bt(const u16* __restrict__ A, long long sAz, int lda,
             const u16* __restrict__ Bp, long long sBz, int ldb,
             void* __restrict__ Cp, long long sCz, int ldc,
             const float* __restrict__ bias, int K, float alpha) {
    constexpr int NT = WM * WN * 64;
    constexpr int BK = 64;
    constexpr int AI = (BM * BK) / (NT * 8);
    constexpr int BI = (BN * BK) / (NT * 8);
    static_assert(AI >= 1 && (BM * BK) % (NT * 8) == 0, "A staging");
    static_assert(BI >= 1 && (BN * BK) % (NT * 8) == 0, "B staging");
    static_assert(BM == WM * 64 && BN == WN * 64, "wave tiling");

    __shared__ alignas(16) u16 As[2][BM * BK];
    __shared__ alignas(16) u16 Bs[2][BN * BK];

    const int z = blockIdx.z;
    const u16* Ag = A + (long long)z * sAz;
    const u16* Bg = Bp + (long long)z * sBz;

    const int tid = threadIdx.x;
    const int lane = tid & 63;
    const int w = tid >> 6;
    const int wm = w / WN;
    const int wn = w % WN;
    const int rowBase = blockIdx.y * BM;
    const int colBase = blockIdx.x * BN;
    const int quad = lane >> 4;
    const int frow = lane & 15;

    auto stage = [&](int buf, int k0) {
#pragma unroll
        for (int i = 0; i < AI; i++) {
            int e = (i * NT + tid) * 8;
            int row = e >> 6;
            int gcol = (((e & 63) >> 3) ^ (row & 7)) * 8;   // src-side swizzle
            const u16* g = Ag + (long long)(rowBase + row) * lda + k0 + gcol;
            __builtin_amdgcn_global_load_lds(
                (const __attribute__((address_space(1))) uint32_t*)g,
                (__attribute__((address_space(3))) uint32_t*)(&As[buf][0] + e), 16, 0, 0);
        }
#pragma unroll
        for (int i = 0; i < BI; i++) {
            int e = (i * NT + tid) * 8;
            int row = e >> 6;
            int gcol = (((e & 63) >> 3) ^ (row & 7)) * 8;
            const u16* g = Bg + (long long)(colBase + row) * ldb + k0 + gcol;
            __builtin_amdgcn_global_load_lds(
                (const __attribute__((address_space(1))) uint32_t*)g,
                (__attribute__((address_space(3))) uint32_t*)(&Bs[buf][0] + e), 16, 0, 0);
        }
    };

    f32x4 acc[4][4] = {};

    const int nk = K / BK;
    stage(0, 0);
    __syncthreads();

#pragma unroll 1
    for (int t = 0; t < nk; ++t) {
        const int cur = t & 1;
        if (t + 1 < nk) stage(cur ^ 1, (t + 1) * BK);

#pragma unroll
        for (int kk = 0; kk < 2; kk++) {
            bf16x8 af[4], bfr[4];
#pragma unroll
            for (int mt = 0; mt < 4; mt++) {
                int row = wm * 64 + mt * 16 + frow;
                af[mt] = *(const bf16x8*)&As[cur][row * 64 + (((kk * 4 + quad) ^ (frow & 7)) * 8)];
            }
#pragma unroll
            for (int nt = 0; nt < 4; nt++) {
                int row = wn * 64 + nt * 16 + frow;
                bfr[nt] = *(const bf16x8*)&Bs[cur][row * 64 + (((kk * 4 + quad) ^ (frow & 7)) * 8)];
            }
#pragma unroll
            for (int mt = 0; mt < 4; mt++)
#pragma unroll
                for (int nt = 0; nt < 4; nt++)
                    acc[mt][nt] = __builtin_amdgcn_mfma_f32_16x16x32_bf16(
                        af[mt], bfr[nt], acc[mt][nt], 0, 0, 0);
        }

        __syncthreads();
    }

    const int r0 = rowBase + wm * 64;
    const int c0 = colBase + wn * 64;
    const int rl = (lane >> 4) * 4;
    const int cl = lane & 15;
#pragma unroll
    for (int mt = 0; mt < 4; mt++) {
#pragma unroll
        for (int nt = 0; nt < 4; nt++) {
#pragma unroll
            for (int r = 0; r < 4; r++) {
                int row = r0 + mt * 16 + rl + r;
                int col = c0 + nt * 16 + cl;
                float v = acc[mt][nt][r] * alpha;
                if (HASBIAS) v += bias[col];
                if (OUTF32)
                    ((float*)Cp)[(long long)z * sCz + (long long)row * ldc + col] = v;
                else
                    ((u16*)Cp)[(long long)z * sCz + (long long)row * ldc + col] = f2bf_hw(v);
            }
        }
    }
}

// ---------------------------------------------------------------------------
// Transpose to bf16: in [rows,cols] (fp32 if INF32 else bf16) -> [cols,rows].
// ---------------------------------------------------------------------------
template<bool INF32>
__global__ __launch_bounds__(256)
void transpose_to_bf16(const void* __restrict__ in, u16* __restrict__ out,
                       int rows, int cols, long long sInZ, long long sOutZ) {
    __shared__ u16 tile[32][33];
    const int z = blockIdx.z;
    const int c0 = blockIdx.x * 32, r0 = blockIdx.y * 32;
    const int tx = threadIdx.x, ty = threadIdx.y;
#pragma unroll
    for (int i = 0; i < 32; i += 8) {
        long long off = (long long)z * sInZ + (long long)(r0 + ty + i) * cols + c0 + tx;
        tile[ty + i][tx] = INF32 ? f2bf(((const float*)in)[off]) : ((const u16*)in)[off];
    }
    __syncthreads();
#pragma unroll
    for (int i = 0; i < 32; i += 8)
        out[(long long)z * sOutZ + (long long)(c0 + ty + i) * rows + r0 + tx] = tile[tx][ty + i];
}

// ---------------------------------------------------------------------------
// Fused flash attention v8.
//  - v7 T14 async-stage was NEUTRAL (47.1 -> 47.4): Us latency was already
//    TLP-hidden. Counters: VALUBusy 42% = 4x MfmaUtil -> softmax VALU is the
//    dominant consumer. v8 cuts VALU:
//    (a) P-write + epilogue use native __bf16 cast (v_cvt_pk_bf16_f32, RTNE)
//        instead of ~4-op hand-rolled f2bf (32/thread/iter).
//    (b) causal-mask fixup hoisted under uniform if(last) branch.
//  - Structure = v6 split-wait (measured best): Us(2)+Vs(2) gload_lds,
//    vmcnt(2)+barrier -> S-MFMA overlaps Vs flight; vmcnt(0)+barrier -> PV.
// In-place y into v is race-free: block reads only its own q-slice of v.
// ---------------------------------------------------------------------------
#define LOG2E 1.44269504f

__global__ __launch_bounds__(512)
void flash_attn(const u16* __restrict__ v, const u16* __restrict__ U,
                const u16* __restrict__ vT, const float* __restrict__ bc,
                u16* __restrict__ y) {
    __shared__ alignas(16) u16 Us[128 * 64];    // [key][chunk^key&7] (swizzled)
    __shared__ alignas(16) u16 Vs[64 * 128];    // [dim][chunk^dim&15] (swizzled)
    __shared__ alignas(16) u16 Ps[128 * 136];   // q x keys, stride 136
    __shared__ u16 bcs[Tz];                     // bf16(bc * log2e)

    // grid remap: 768 = 8 xcd x 96 slots; xcd-affine columns, heavy qi first
    const int bi = blockIdx.x;
    const int xcd = bi & 7;
    const int slot = bi >> 3;                   // 0..95
    const int col = (slot % 12) * 8 + xcd;      // 0..95, col%8 == xcd
    const int qi = 7 - slot / 12;               // 0..7, heavy tiles first
    const int b = col / NHz, h = col % NHz;

    const int tid = threadIdx.x, lane = tid & 63, w = tid >> 6;
    const int quad = lane >> 4, cl = lane & 15;
    const int q0 = qi * 128;
    const int wrow = w * 16;                    // wave's 16 q-rows (w 0..7)

    for (int j = tid; j < Tz; j += 512) bcs[j] = f2bf(bc[j] * LOG2E);

    // resident A-fragments of vq (this block's own 128x64 slice)
    const u16* vq = v + ((long long)b * Tz + q0) * Cz + h * HDz;
    bf16x8 aS[2];
#pragma unroll
    for (int ks = 0; ks < 2; ks++)
        aS[ks] = *(const bf16x8*)(vq + (long long)(wrow + cl) * Cz + ks * 32 + quad * 8);

    f32x4 Oacc[4] = {};
    float mrow[4], lrow[4];
#pragma unroll
    for (int r = 0; r < 4; r++) { mrow[r] = -3.0e38f; lrow[r] = 0.f; }

    const u16* Ub = U + (long long)b * Tz * Cz + h * HDz;
    const u16* Vb = vT + ((long long)b * Cz + h * HDz) * Tz;

    __syncthreads();   // bcs visible; drains pre-loop VMEM

    const int kts = qi + 1;   // # of 128-wide k-tiles covering [0, q0+128)
    for (int kt = 0; kt < kts; kt++) {
        if (kt) __builtin_amdgcn_s_barrier();   // WAR: all waves done with Us/Vs
        const u16* Ug = Ub + (long long)kt * 128 * Cz;
#pragma unroll
        for (int i = 0; i < 2; i++) {           // Us first (waited by vmcnt(2))
            int e = (i * 512 + tid) * 8;
            int key = e >> 6;
            int ch = ((e & 63) >> 3) ^ (key & 7);   // global-side swizzle
            __builtin_amdgcn_global_load_lds(
                (const __attribute__((address_space(1))) uint32_t*)(Ug + (long long)key * Cz + ch * 8),
                (__attribute__((address_space(3))) uint32_t*)(Us + e), 16, 0, 0);
        }
        const u16* Vg = Vb + kt * 128;
#pragma unroll
        for (int i = 0; i < 2; i++) {           // Vs second (stays in flight)
            int e = (i * 512 + tid) * 8;
            int dim = e >> 7;
            int ch = ((e & 127) >> 3) ^ (dim & 15);  // global-side swizzle
            __builtin_amdgcn_global_load_lds(
                (const __attribute__((address_space(1))) uint32_t*)(Vg + (long long)dim * Tz + ch * 8),
                (__attribute__((address_space(3))) uint32_t*)(Vs + e), 16, 0, 0);
        }
        // own Us landed (in-order retire); Vs (newest 2) may still be in flight
        asm volatile("s_waitcnt vmcnt(2)" ::: "memory");
        __builtin_amdgcn_s_barrier();           // all waves' Us landed

        // S = vq . Uk^T  (wave tile 16 x 128) — overlaps Vs flight time
        f32x4 S[8] = {};
        __builtin_amdgcn_s_setprio(1);
#pragma unroll
        for (int ks = 0; ks < 2; ks++)
#pragma unroll
            for (int nt = 0; nt < 8; nt++) {
                int key = nt * 16 + cl;
                bf16x8 bS = *(const bf16x8*)&Us[key * 64 + (((ks * 4 + quad) ^ (key & 7)) * 8)];
                S[nt] = __builtin_amdgcn_mfma_f32_16x16x32_bf16(aS[ks], bS, S[nt], 0, 0, 0);
            }
        __builtin_amdgcn_s_setprio(0);

        const bool last = (kt == kts - 1);
#pragma unroll
        for (int nt = 0; nt < 8; nt++) {
            float bl = bf2f(bcs[kt * 128 + nt * 16 + cl]);
#pragma unroll
            for (int r = 0; r < 4; r++)
                S[nt][r] = S[nt][r] * (0.125f * LOG2E) + bl;
        }
        if (last) {                             // uniform branch: mask fixup
            int rowg = q0 + wrow + quad * 4;
#pragma unroll
            for (int nt = 0; nt < 8; nt++) {
                int colg = kt * 128 + nt * 16 + cl;
#pragma unroll
                for (int r = 0; r < 4; r++)
                    if (colg > rowg + r) S[nt][r] = -3.0e38f;
            }
        }

        // row max (regs, then across the 16 lanes of the quad group)
        float mnew[4], alpha[4];
#pragma unroll
        for (int r = 0; r < 4; r++) {
            float m = S[0][r];
#pragma unroll
            for (int nt = 1; nt < 8; nt++) m = fmaxf(m, S[nt][r]);
#pragma unroll
            for (int d = 1; d < 16; d <<= 1) m = fmaxf(m, __shfl_xor(m, d));
            mnew[r] = fmaxf(mrow[r], m);
            alpha[r] = __builtin_amdgcn_exp2f(mrow[r] - mnew[r]);
            mrow[r] = mnew[r];
        }

        // P = exp2(S - m) -> LDS (wave-private rows), accumulate row sums
        float psum[4] = {};
#pragma unroll
        for (int nt = 0; nt < 8; nt++)
#pragma unroll
            for (int r = 0; r < 4; r++) {
                float p = __builtin_amdgcn_exp2f(S[nt][r] - mnew[r]);
                psum[r] += p;
                Ps[(wrow + quad * 4 + r) * 136 + nt * 16 + cl] = f2bf_hw(p);
            }
#pragma unroll
        for (int r = 0; r < 4; r++) {
            float s = psum[r];
#pragma unroll
            for (int d = 1; d < 16; d <<= 1) s += __shfl_xor(s, d);
            lrow[r] = lrow[r] * alpha[r] + s;
#pragma unroll
            for (int nt2 = 0; nt2 < 4; nt2++)
                Oacc[nt2][r] *= alpha[r];
        }

        // own Vs landed; barrier -> all waves' Vs landed
        asm volatile("s_waitcnt vmcnt(0)" ::: "memory");
        __builtin_amdgcn_s_barrier();

        // O += P . Vk   (K = 128)
        __builtin_amdgcn_s_setprio(1);
#pragma unroll
        for (int ks = 0; ks < 4; ks++) {
            bf16x8 pA = *(const bf16x8*)&Ps[(wrow + cl) * 136 + ks * 32 + quad * 8];
#pragma unroll
            for (int nt2 = 0; nt2 < 4; nt2++) {
                int dim = nt2 * 16 + cl;
                bf16x8 vB = *(const bf16x8*)&Vs[dim * 128 + (((ks * 4 + quad) ^ cl) * 8)];
                Oacc[nt2] = __builtin_amdgcn_mfma_f32_16x16x32_bf16(pA, vB, Oacc[nt2], 0, 0, 0);
            }
        }
        __builtin_amdgcn_s_setprio(0);
    }

    // epilogue: O /= l, write y (in-place into v's own region)
    u16* yq = y + ((long long)b * Tz + q0) * Cz + h * HDz;
#pragma unroll
    for (int r = 0; r < 4; r++) {
        float inv = 1.f / lrow[r];
#pragma unroll
        for (int nt2 = 0; nt2 < 4; nt2++)
            yq[(long long)(wrow + quad * 4 + r) * Cz + nt2 * 16 + cl] =
                f2bf_hw(Oacc[nt2][r] * inv);
    }
}

// ---------------------------------------------------------------------------
extern "C" void kernel_launch(void* const* d_in, const int* in_sizes, int n_in,
                              void* d_out, int out_size, void* d_ws, size_t ws_size,
                              hipStream_t stream) {
    const float* x  = (const float*)d_in[0];
    const float* Wv = (const float*)d_in[1];
    const float* bv = (const float*)d_in[2];
    const float* Wl = (const float*)d_in[3];
    const float* Wc = (const float*)d_in[4];
    const float* bc = (const float*)d_in[5];
    const float* Wp = (const float*)d_in[6];
    const float* bp = (const float*)d_in[7];

    // ws (bf16 elems, ~59 MB): xb, Wvb, Wcb, Wpb, WlT, Wcl, vbf, vT, U
    u16* ws  = (u16*)d_ws;
    u16* xb  = ws;
    u16* Wvb = xb  + (size_t)Bz * Tz * Cz;
    u16* Wcb = Wvb + (size_t)Cz * Cz;
    u16* Wpb = Wcb + (size_t)Tz * Tz;
    u16* WlT = Wpb + (size_t)Cz * Cz;
    u16* Wcl = WlT + (size_t)Tz * Tz;
    u16* vbf = Wcl + (size_t)Tz * Tz;
    u16* vT  = vbf + (size_t)Bz * Tz * Cz;
    u16* U   = vT  + (size_t)Bz * Tz * Cz;

    const long long sTC = (long long)Tz * Cz;
    const long long sCT = (long long)Cz * Tz;

    // 0) one-time bf16 conversions (single fused launch)
    cvt_all<<<(N4_ALL + 255) / 256, 256, 0, stream>>>(x, Wv, Wc, Wp, xb, Wvb, Wcb, Wpb);
    // 1) WlT = Wl^T (fp32 -> bf16)
    transpose_to_bf16<true><<<dim3(32, 32, 1), dim3(32, 8), 0, stream>>>(Wl, WlT, Tz, Tz, 0, 0);
    // 2) Wcl = Wcb . WlT^T = Wc @ Wl — 64^2 tile, 256 blocks = 1/CU
    gemm_bt<64, 64, 1, 1, false, false><<<dim3(Tz / 64, Tz / 64, 1), 64, 0, stream>>>(
        Wcb, 0, Tz, WlT, 0, Tz, Wcl, 0, Tz, nullptr, Tz, 1.f);
    // 3) v = xb . Wvb^T + bv — 128^2, BK=64
    gemm_bt<128, 128, 2, 2, false, true><<<dim3(Cz / 128, (Bz * Tz) / 128, 1), 256, 0, stream>>>(
        xb, 0, Cz, Wvb, 0, Cz, vbf, 0, Cz, bv, Cz, 1.f);
    // 4) vT[b] = v[b]^T
    transpose_to_bf16<false><<<dim3(Cz / 32, Tz / 32, Bz), dim3(32, 8), 0, stream>>>(
        vbf, vT, Tz, Cz, sTC, sCT);
    // 5) U[b] = Wcl @ v[b]  (= Wcl . vT[b]^T), K=T — 128^2, BK=64
    gemm_bt<128, 128, 2, 2, false, false><<<dim3(Cz / 128, Tz / 128, Bz), 256, 0, stream>>>(
        Wcl, 0, Tz, vT, sCT, Tz, U, sTC, Cz, nullptr, Tz, 1.f);
    // 6) fused logits -> causal softmax -> P.V, y in-place into vbf
    flash_attn<<<dim3(8 * NHz * Bz, 1, 1), 512, 0, stream>>>(vbf, U, vT, bc, vbf);
    // 7) out = y . Wpb^T + bp  (fp32 out) — 128^2, BK=64
    gemm_bt<128, 128, 2, 2, true, true><<<dim3(Cz / 128, (Bz * Tz) / 128, 1), 256, 0, stream>>>(
        vbf, 0, Cz, Wpb, 0, Cz, (float*)d_out, 0, Cz, bp, Cz, 1.f);
}

// Round 13
// 210.644 us; speedup vs baseline: 1.2528x; 1.0506x over previous
//
#include <hip/hip_runtime.h>
#include <stdint.h>

#define Bz 8
#define Tz 1024
#define Cz 768
#define NHz 12
#define HDz 64

typedef unsigned short u16;
typedef __attribute__((ext_vector_type(8))) __bf16 bf16x8;
typedef __attribute__((ext_vector_type(4))) float f32x4;
typedef __attribute__((ext_vector_type(4))) unsigned int u32x4;

__device__ __forceinline__ float bf2f(u16 b) {
    union { uint32_t u; float f; } c; c.u = ((uint32_t)b) << 16; return c.f;
}
__device__ __forceinline__ u16 f2bf(float f) {
    union { float f; uint32_t u; } c; c.f = f;
    uint32_t u = c.u;
    return (u16)((u + 0x7fffu + ((u >> 16) & 1u)) >> 16);
}
__device__ __forceinline__ u16 f2bf_hw(float f) {   // native RTNE cast
    __bf16 b = (__bf16)f;
    union { __bf16 b; u16 u; } c; c.b = b; return c.u;
}

// s_waitcnt helpers: wait vmcnt<=VM (lgkm/exp unconstrained), and lgkm==0 only.
// simm16 = vm[3:0] | exp(3b)<<4 | lgkm(4b)<<8 | vm[5:4]<<14
template<unsigned VM>
__device__ __forceinline__ void wait_vm() {
    __builtin_amdgcn_s_waitcnt((VM & 15u) | (7u << 4) | (15u << 8) | ((VM >> 4) << 14));
}
__device__ __forceinline__ void wait_lgkm0() {
    __builtin_amdgcn_s_waitcnt(15u | (7u << 4) | (0u << 8) | (3u << 14));
}

// ---------------------------------------------------------------------------
// Fused fp32 -> bf16 elementwise convert for all 4 input tensors (1 launch).
// ---------------------------------------------------------------------------
#define N4_X  (Bz * Tz * Cz / 4)
#define N4_WV (Cz * Cz / 4)
#define N4_WC (Tz * Tz / 4)
#define N4_WP (Cz * Cz / 4)
#define N4_ALL (N4_X + N4_WV + N4_WC + N4_WP)

__global__ __launch_bounds__(256)
void cvt_all(const float* __restrict__ x, const float* __restrict__ wv,
             const float* __restrict__ wc, const float* __restrict__ wp,
             u16* __restrict__ xb, u16* __restrict__ wvb,
             u16* __restrict__ wcb, u16* __restrict__ wpb) {
    int i = blockIdx.x * 256 + threadIdx.x;
    if (i >= N4_ALL) return;
    const float* in;
    u16* out;
    if (i < N4_X) {
        in = x; out = xb;
    } else if (i < N4_X + N4_WV) {
        in = wv; out = wvb; i -= N4_X;
    } else if (i < N4_X + N4_WV + N4_WC) {
        in = wc; out = wcb; i -= N4_X + N4_WV;
    } else {
        in = wp; out = wpb; i -= N4_X + N4_WV + N4_WC;
    }
    float4 v = ((const float4*)in)[i];
    union { u16 h[4]; uint2 u; } o;
    o.h[0] = f2bf(v.x); o.h[1] = f2bf(v.y); o.h[2] = f2bf(v.z); o.h[3] = f2bf(v.w);
    ((uint2*)out)[i] = o.u;
}

// ---------------------------------------------------------------------------
// C = alpha * (A . B^T) [+ bias_col]   MFMA 16x16x32, all-bf16 operands.
// BK=64 + T4 counted-vmcnt pipeline (no vmcnt(0) drain in steady state):
//   per iter: ds_read frags -> lgkm0+barrier (WAR) -> stage(t+2) -> MFMA
//   -> vmcnt(L) (tile t+1 landed; stage(t+2) stays in flight) -> barrier.
//   Staging gets a FULL iteration to land vs ~300cy under the old
//   __syncthreads drain. Same protocol flash v5/v6 validated on HW.
// A/B staged with global-source chunk XOR swizzle (ch ^= row&7); readers
// XOR back -> full 32-bank spread on ds_read_b128.
// ---------------------------------------------------------------------------
template<int BM, int BN, int WM, int WN, bool OUTF32, bool HASBIAS>
__global__ __launch_bounds__(WM * WN * 64)
void gemm_bt(const u16* __restrict__ A, long long sAz, int lda,
             const u16* __restrict__ Bp, long long sBz, int ldb,
             void* __restrict__ Cp, long long sCz, int ldc,
             const float* __restrict__ bias, int K, float alpha) {
    constexpr int NT = WM * WN * 64;
    constexpr int BK = 64;
    constexpr int AI = (BM * BK) / (NT * 8);
    constexpr int BI = (BN * BK) / (NT * 8);
    constexpr unsigned LD = AI + BI;           // gload_lds per stage()
    static_assert(AI >= 1 && (BM * BK) % (NT * 8) == 0, "A staging");
    static_assert(BI >= 1 && (BN * BK) % (NT * 8) == 0, "B staging");
    static_assert(BM == WM * 64 && BN == WN * 64, "wave tiling");

    __shared__ alignas(16) u16 As[2][BM * BK];
    __shared__ alignas(16) u16 Bs[2][BN * BK];

    const int z = blockIdx.z;
    const u16* Ag = A + (long long)z * sAz;
    const u16* Bg = Bp + (long long)z * sBz;

    const int tid = threadIdx.x;
    const int lane = tid & 63;
    const int w = tid >> 6;
    const int wm = w / WN;
    const int wn = w % WN;
    const int rowBase = blockIdx.y * BM;
    const int colBase = blockIdx.x * BN;
    const int quad = lane >> 4;
    const int frow = lane & 15;

    auto stage = [&](int buf, int k0) {
#pragma unroll
        for (int i = 0; i < AI; i++) {
            int e = (i * NT + tid) * 8;
            int row = e >> 6;
            int gcol = (((e & 63) >> 3) ^ (row & 7)) * 8;   // src-side swizzle
            const u16* g = Ag + (long long)(rowBase + row) * lda + k0 + gcol;
            __builtin_amdgcn_global_load_lds(
                (const __attribute__((address_space(1))) uint32_t*)g,
                (__attribute__((address_space(3))) uint32_t*)(&As[buf][0] + e), 16, 0, 0);
        }
#pragma unroll
        for (int i = 0; i < BI; i++) {
            int e = (i * NT + tid) * 8;
            int row = e >> 6;
            int gcol = (((e & 63) >> 3) ^ (row & 7)) * 8;
            const u16* g = Bg + (long long)(colBase + row) * ldb + k0 + gcol;
            __builtin_amdgcn_global_load_lds(
                (const __attribute__((address_space(1))) uint32_t*)g,
                (__attribute__((address_space(3))) uint32_t*)(&Bs[buf][0] + e), 16, 0, 0);
        }
    };

    f32x4 acc[4][4] = {};

    const int nk = K / BK;
    stage(0, 0);
    if (nk > 1) { stage(1, BK); wait_vm<LD>(); }   // tile0 landed; tile1 in flight
    else        { wait_vm<0>(); }
    __builtin_amdgcn_s_barrier();                  // all waves' tile0 landed

#pragma unroll 1
    for (int t = 0; t < nk; ++t) {
        const int cur = t & 1;

        // read ALL fragments of tile t into regs
        bf16x8 af[2][4], bfr[2][4];
#pragma unroll
        for (int kk = 0; kk < 2; kk++) {
#pragma unroll
            for (int mt = 0; mt < 4; mt++) {
                int row = wm * 64 + mt * 16 + frow;
                af[kk][mt] = *(const bf16x8*)&As[cur][row * 64 + (((kk * 4 + quad) ^ (frow & 7)) * 8)];
            }
#pragma unroll
            for (int nt = 0; nt < 4; nt++) {
                int row = wn * 64 + nt * 16 + frow;
                bfr[kk][nt] = *(const bf16x8*)&Bs[cur][row * 64 + (((kk * 4 + quad) ^ (frow & 7)) * 8)];
            }
        }
        wait_lgkm0();                              // our reads retired to regs
        __builtin_amdgcn_s_barrier();              // all waves done reading buf[cur]

        if (t + 2 < nk) stage(cur, (t + 2) * BK);  // overwrite freed buffer

#pragma unroll
        for (int kk = 0; kk < 2; kk++)
#pragma unroll
            for (int mt = 0; mt < 4; mt++)
#pragma unroll
                for (int nt = 0; nt < 4; nt++)
                    acc[mt][nt] = __builtin_amdgcn_mfma_f32_16x16x32_bf16(
                        af[kk][mt], bfr[kk][nt], acc[mt][nt], 0, 0, 0);

        if (t + 2 < nk)       wait_vm<LD>();       // tile t+1 landed; t+2 in flight
        else if (t + 1 < nk)  wait_vm<0>();        // last prefetch landed
        if (t + 1 < nk) __builtin_amdgcn_s_barrier();
    }

    const int r0 = rowBase + wm * 64;
    const int c0 = colBase + wn * 64;
    const int rl = (lane >> 4) * 4;
    const int cl = lane & 15;
#pragma unroll
    for (int mt = 0; mt < 4; mt++) {
#pragma unroll
        for (int nt = 0; nt < 4; nt++) {
#pragma unroll
            for (int r = 0; r < 4; r++) {
                int row = r0 + mt * 16 + rl + r;
                int col = c0 + nt * 16 + cl;
                float v = acc[mt][nt][r] * alpha;
                if (HASBIAS) v += bias[col];
                if (OUTF32)
                    ((float*)Cp)[(long long)z * sCz + (long long)row * ldc + col] = v;
                else
                    ((u16*)Cp)[(long long)z * sCz + (long long)row * ldc + col] = f2bf_hw(v);
            }
        }
    }
}

// ---------------------------------------------------------------------------
// Transpose to bf16: in [rows,cols] (fp32 if INF32 else bf16) -> [cols,rows].
// ---------------------------------------------------------------------------
template<bool INF32>
__global__ __launch_bounds__(256)
void transpose_to_bf16(const void* __restrict__ in, u16* __restrict__ out,
                       int rows, int cols, long long sInZ, long long sOutZ) {
    __shared__ u16 tile[32][33];
    const int z = blockIdx.z;
    const int c0 = blockIdx.x * 32, r0 = blockIdx.y * 32;
    const int tx = threadIdx.x, ty = threadIdx.y;
#pragma unroll
    for (int i = 0; i < 32; i += 8) {
        long long off = (long long)z * sInZ + (long long)(r0 + ty + i) * cols + c0 + tx;
        tile[ty + i][tx] = INF32 ? f2bf(((const float*)in)[off]) : ((const u16*)in)[off];
    }
    __syncthreads();
#pragma unroll
    for (int i = 0; i < 32; i += 8)
        out[(long long)z * sOutZ + (long long)(c0 + ty + i) * rows + r0 + tx] = tile[tx][ty + i];
}

// ---------------------------------------------------------------------------
// Fused flash attention v8 (unchanged from R12 measurement: 46.8us).
// v8 verdict: VALU cut worked (VALUBusy 42->36) but duration flat -> flash
// is sync/latency-bound, not VALU-bound. Held constant this round.
// ---------------------------------------------------------------------------
#define LOG2E 1.44269504f

__global__ __launch_bounds__(512)
void flash_attn(const u16* __restrict__ v, const u16* __restrict__ U,
                const u16* __restrict__ vT, const float* __restrict__ bc,
                u16* __restrict__ y) {
    __shared__ alignas(16) u16 Us[128 * 64];    // [key][chunk^key&7] (swizzled)
    __shared__ alignas(16) u16 Vs[64 * 128];    // [dim][chunk^dim&15] (swizzled)
    __shared__ alignas(16) u16 Ps[128 * 136];   // q x keys, stride 136
    __shared__ u16 bcs[Tz];                     // bf16(bc * log2e)

    // grid remap: 768 = 8 xcd x 96 slots; xcd-affine columns, heavy qi first
    const int bi = blockIdx.x;
    const int xcd = bi & 7;
    const int slot = bi >> 3;                   // 0..95
    const int col = (slot % 12) * 8 + xcd;      // 0..95, col%8 == xcd
    const int qi = 7 - slot / 12;               // 0..7, heavy tiles first
    const int b = col / NHz, h = col % NHz;

    const int tid = threadIdx.x, lane = tid & 63, w = tid >> 6;
    const int quad = lane >> 4, cl = lane & 15;
    const int q0 = qi * 128;
    const int wrow = w * 16;                    // wave's 16 q-rows (w 0..7)

    for (int j = tid; j < Tz; j += 512) bcs[j] = f2bf(bc[j] * LOG2E);

    // resident A-fragments of vq (this block's own 128x64 slice)
    const u16* vq = v + ((long long)b * Tz + q0) * Cz + h * HDz;
    bf16x8 aS[2];
#pragma unroll
    for (int ks = 0; ks < 2; ks++)
        aS[ks] = *(const bf16x8*)(vq + (long long)(wrow + cl) * Cz + ks * 32 + quad * 8);

    f32x4 Oacc[4] = {};
    float mrow[4], lrow[4];
#pragma unroll
    for (int r = 0; r < 4; r++) { mrow[r] = -3.0e38f; lrow[r] = 0.f; }

    const u16* Ub = U + (long long)b * Tz * Cz + h * HDz;
    const u16* Vb = vT + ((long long)b * Cz + h * HDz) * Tz;

    __syncthreads();   // bcs visible; drains pre-loop VMEM

    const int kts = qi + 1;   // # of 128-wide k-tiles covering [0, q0+128)
    for (int kt = 0; kt < kts; kt++) {
        if (kt) __builtin_amdgcn_s_barrier();   // WAR: all waves done with Us/Vs
        const u16* Ug = Ub + (long long)kt * 128 * Cz;
#pragma unroll
        for (int i = 0; i < 2; i++) {           // Us first (waited by vmcnt(2))
            int e = (i * 512 + tid) * 8;
            int key = e >> 6;
            int ch = ((e & 63) >> 3) ^ (key & 7);   // global-side swizzle
            __builtin_amdgcn_global_load_lds(
                (const __attribute__((address_space(1))) uint32_t*)(Ug + (long long)key * Cz + ch * 8),
                (__attribute__((address_space(3))) uint32_t*)(Us + e), 16, 0, 0);
        }
        const u16* Vg = Vb + kt * 128;
#pragma unroll
        for (int i = 0; i < 2; i++) {           // Vs second (stays in flight)
            int e = (i * 512 + tid) * 8;
            int dim = e >> 7;
            int ch = ((e & 127) >> 3) ^ (dim & 15);  // global-side swizzle
            __builtin_amdgcn_global_load_lds(
                (const __attribute__((address_space(1))) uint32_t*)(Vg + (long long)dim * Tz + ch * 8),
                (__attribute__((address_space(3))) uint32_t*)(Vs + e), 16, 0, 0);
        }
        // own Us landed (in-order retire); Vs (newest 2) may still be in flight
        asm volatile("s_waitcnt vmcnt(2)" ::: "memory");
        __builtin_amdgcn_s_barrier();           // all waves' Us landed

        // S = vq . Uk^T  (wave tile 16 x 128) — overlaps Vs flight time
        f32x4 S[8] = {};
        __builtin_amdgcn_s_setprio(1);
#pragma unroll
        for (int ks = 0; ks < 2; ks++)
#pragma unroll
            for (int nt = 0; nt < 8; nt++) {
                int key = nt * 16 + cl;
                bf16x8 bS = *(const bf16x8*)&Us[key * 64 + (((ks * 4 + quad) ^ (key & 7)) * 8)];
                S[nt] = __builtin_amdgcn_mfma_f32_16x16x32_bf16(aS[ks], bS, S[nt], 0, 0, 0);
            }
        __builtin_amdgcn_s_setprio(0);

        const bool last = (kt == kts - 1);
#pragma unroll
        for (int nt = 0; nt < 8; nt++) {
            float bl = bf2f(bcs[kt * 128 + nt * 16 + cl]);
#pragma unroll
            for (int r = 0; r < 4; r++)
                S[nt][r] = S[nt][r] * (0.125f * LOG2E) + bl;
        }
        if (last) {                             // uniform branch: mask fixup
            int rowg = q0 + wrow + quad * 4;
#pragma unroll
            for (int nt = 0; nt < 8; nt++) {
                int colg = kt * 128 + nt * 16 + cl;
#pragma unroll
                for (int r = 0; r < 4; r++)
                    if (colg > rowg + r) S[nt][r] = -3.0e38f;
            }
        }

        // row max (regs, then across the 16 lanes of the quad group)
        float mnew[4], alpha[4];
#pragma unroll
        for (int r = 0; r < 4; r++) {
            float m = S[0][r];
#pragma unroll
            for (int nt = 1; nt < 8; nt++) m = fmaxf(m, S[nt][r]);
#pragma unroll
            for (int d = 1; d < 16; d <<= 1) m = fmaxf(m, __shfl_xor(m, d));
            mnew[r] = fmaxf(mrow[r], m);
            alpha[r] = __builtin_amdgcn_exp2f(mrow[r] - mnew[r]);
            mrow[r] = mnew[r];
        }

        // P = exp2(S - m) -> LDS (wave-private rows), accumulate row sums
        float psum[4] = {};
#pragma unroll
        for (int nt = 0; nt < 8; nt++)
#pragma unroll
            for (int r = 0; r < 4; r++) {
                float p = __builtin_amdgcn_exp2f(S[nt][r] - mnew[r]);
                psum[r] += p;
                Ps[(wrow + quad * 4 + r) * 136 + nt * 16 + cl] = f2bf_hw(p);
            }
#pragma unroll
        for (int r = 0; r < 4; r++) {
            float s = psum[r];
#pragma unroll
            for (int d = 1; d < 16; d <<= 1) s += __shfl_xor(s, d);
            lrow[r] = lrow[r] * alpha[r] + s;
#pragma unroll
            for (int nt2 = 0; nt2 < 4; nt2++)
                Oacc[nt2][r] *= alpha[r];
        }

        // own Vs landed; barrier -> all waves' Vs landed
        asm volatile("s_waitcnt vmcnt(0)" ::: "memory");
        __builtin_amdgcn_s_barrier();

        // O += P . Vk   (K = 128)
        __builtin_amdgcn_s_setprio(1);
#pragma unroll
        for (int ks = 0; ks < 4; ks++) {
            bf16x8 pA = *(const bf16x8*)&Ps[(wrow + cl) * 136 + ks * 32 + quad * 8];
#pragma unroll
            for (int nt2 = 0; nt2 < 4; nt2++) {
                int dim = nt2 * 16 + cl;
                bf16x8 vB = *(const bf16x8*)&Vs[dim * 128 + (((ks * 4 + quad) ^ cl) * 8)];
                Oacc[nt2] = __builtin_amdgcn_mfma_f32_16x16x32_bf16(pA, vB, Oacc[nt2], 0, 0, 0);
            }
        }
        __builtin_amdgcn_s_setprio(0);
    }

    // epilogue: O /= l, write y (in-place into v's own region)
    u16* yq = y + ((long long)b * Tz + q0) * Cz + h * HDz;
#pragma unroll
    for (int r = 0; r < 4; r++) {
        float inv = 1.f / lrow[r];
#pragma unroll
        for (int nt2 = 0; nt2 < 4; nt2++)
            yq[(long long)(wrow + quad * 4 + r) * Cz + nt2 * 16 + cl] =
                f2bf_hw(Oacc[nt2][r] * inv);
    }
}

// ---------------------------------------------------------------------------
extern "C" void kernel_launch(void* const* d_in, const int* in_sizes, int n_in,
                              void* d_out, int out_size, void* d_ws, size_t ws_size,
                              hipStream_t stream) {
    const float* x  = (const float*)d_in[0];
    const float* Wv = (const float*)d_in[1];
    const float* bv = (const float*)d_in[2];
    const float* Wl = (const float*)d_in[3];
    const float* Wc = (const float*)d_in[4];
    const float* bc = (const float*)d_in[5];
    const float* Wp = (const float*)d_in[6];
    const float* bp = (const float*)d_in[7];

    // ws (bf16 elems, ~59 MB): xb, Wvb, Wcb, Wpb, WlT, Wcl, vbf, vT, U
    u16* ws  = (u16*)d_ws;
    u16* xb  = ws;
    u16* Wvb = xb  + (size_t)Bz * Tz * Cz;
    u16* Wcb = Wvb + (size_t)Cz * Cz;
    u16* Wpb = Wcb + (size_t)Tz * Tz;
    u16* WlT = Wpb + (size_t)Cz * Cz;
    u16* Wcl = WlT + (size_t)Tz * Tz;
    u16* vbf = Wcl + (size_t)Tz * Tz;
    u16* vT  = vbf + (size_t)Bz * Tz * Cz;
    u16* U   = vT  + (size_t)Bz * Tz * Cz;

    const long long sTC = (long long)Tz * Cz;
    const long long sCT = (long long)Cz * Tz;

    // 0) one-time bf16 conversions (single fused launch)
    cvt_all<<<(N4_ALL + 255) / 256, 256, 0, stream>>>(x, Wv, Wc, Wp, xb, Wvb, Wcb, Wpb);
    // 1) WlT = Wl^T (fp32 -> bf16)
    transpose_to_bf16<true><<<dim3(32, 32, 1), dim3(32, 8), 0, stream>>>(Wl, WlT, Tz, Tz, 0, 0);
    // 2) Wcl = Wcb . WlT^T = Wc @ Wl — 64^2 tile, 256 blocks = 1/CU
    gemm_bt<64, 64, 1, 1, false, false><<<dim3(Tz / 64, Tz / 64, 1), 64, 0, stream>>>(
        Wcb, 0, Tz, WlT, 0, Tz, Wcl, 0, Tz, nullptr, Tz, 1.f);
    // 3) v = xb . Wvb^T + bv — 128^2, BK=64, counted-vmcnt pipeline
    gemm_bt<128, 128, 2, 2, false, true><<<dim3(Cz / 128, (Bz * Tz) / 128, 1), 256, 0, stream>>>(
        xb, 0, Cz, Wvb, 0, Cz, vbf, 0, Cz, bv, Cz, 1.f);
    // 4) vT[b] = v[b]^T
    transpose_to_bf16<false><<<dim3(Cz / 32, Tz / 32, Bz), dim3(32, 8), 0, stream>>>(
        vbf, vT, Tz, Cz, sTC, sCT);
    // 5) U[b] = Wcl @ v[b]  (= Wcl . vT[b]^T), K=T — 128^2, BK=64
    gemm_bt<128, 128, 2, 2, false, false><<<dim3(Cz / 128, Tz / 128, Bz), 256, 0, stream>>>(
        Wcl, 0, Tz, vT, sCT, Tz, U, sTC, Cz, nullptr, Tz, 1.f);
    // 6) fused logits -> causal softmax -> P.V, y in-place into vbf
    flash_attn<<<dim3(8 * NHz * Bz, 1, 1), 512, 0, stream>>>(vbf, U, vT, bc, vbf);
    // 7) out = y . Wpb^T + bp  (fp32 out) — 128^2, BK=64
    gemm_bt<128, 128, 2, 2, true, true><<<dim3(Cz / 128, (Bz * Tz) / 128, 1), 256, 0, stream>>>(
        vbf, 0, Cz, Wpb, 0, Cz, (float*)d_out, 0, Cz, bp, Cz, 1.f);
}